// Round 1
// baseline (1927.076 us; speedup 1.0000x reference)
//
#include <hip/hip_runtime.h>

#define B_  4
#define S_  1024
#define D_  1024
#define H_  16
#define DH  64
#define BS  4096   // B_*S_

// ---------------- Wv head-mean reduction ----------------
// v_shared = x @ Wvsh + bvsh, where Wvsh[d][j] = mean_h Wv[d][h*64+j]
__global__ void wv_reduce_kernel(const float* __restrict__ Wv, const float* __restrict__ bv,
                                 float* __restrict__ Wvsh, float* __restrict__ bvsh) {
    int e = blockIdx.x * 256 + threadIdx.x;
    if (e < D_ * DH) {
        int d = e >> 6, j = e & 63;
        float s = 0.f;
#pragma unroll
        for (int h = 0; h < H_; h++) s += Wv[d * D_ + h * DH + j];
        Wvsh[e] = s * (1.f / 16.f);
    }
    if (e < DH) {
        float s = 0.f;
#pragma unroll
        for (int h = 0; h < H_; h++) s += bv[h * DH + e];
        bvsh[e] = s * (1.f / 16.f);
    }
}

// ---------------- 128x128 SGEMM + bias (8x8 micro-tile) ----------------
// C[M,N] = A[M,K] @ Bm[K,N] + bias[N];  M%128==0, N%128==0, K%8==0
__global__ __launch_bounds__(256) void sgemm128(const float* __restrict__ A,
                                                const float* __restrict__ Bm,
                                                const float* __restrict__ bias,
                                                float* __restrict__ C,
                                                int M, int N, int K) {
    __shared__ float As[8][128];
    __shared__ float Bs[8][128];
    int tid = threadIdx.x;
    int bm = blockIdx.y, bn = blockIdx.x;
    int tx = tid & 15, ty = tid >> 4;
    int arow = tid >> 1, acol4 = (tid & 1) * 4;
    int brow = tid >> 5, bcol4 = (tid & 31) * 4;

    float acc[8][8];
#pragma unroll
    for (int i = 0; i < 8; i++)
#pragma unroll
        for (int j = 0; j < 8; j++) acc[i][j] = 0.f;

    const float* Aptr = A + (size_t)(bm * 128 + arow) * K + acol4;
    const float* Bptr = Bm + (size_t)brow * N + bn * 128 + bcol4;

    for (int k0 = 0; k0 < K; k0 += 8) {
        float4 a4 = *(const float4*)(Aptr + k0);
        float4 b4 = *(const float4*)(Bptr + (size_t)k0 * N);
        __syncthreads();
        As[acol4 + 0][arow] = a4.x;
        As[acol4 + 1][arow] = a4.y;
        As[acol4 + 2][arow] = a4.z;
        As[acol4 + 3][arow] = a4.w;
        *(float4*)&Bs[brow][bcol4] = b4;
        __syncthreads();
#pragma unroll
        for (int kk = 0; kk < 8; kk++) {
            float4 a0 = *(float4*)&As[kk][ty * 4];
            float4 a1 = *(float4*)&As[kk][64 + ty * 4];
            float4 b0 = *(float4*)&Bs[kk][tx * 4];
            float4 b1 = *(float4*)&Bs[kk][64 + tx * 4];
            float av[8] = {a0.x, a0.y, a0.z, a0.w, a1.x, a1.y, a1.z, a1.w};
            float bw[8] = {b0.x, b0.y, b0.z, b0.w, b1.x, b1.y, b1.z, b1.w};
#pragma unroll
            for (int i = 0; i < 8; i++)
#pragma unroll
                for (int j = 0; j < 8; j++) acc[i][j] += av[i] * bw[j];
        }
    }
#pragma unroll
    for (int ih = 0; ih < 2; ih++) {
#pragma unroll
        for (int r = 0; r < 4; r++) {
            int row = bm * 128 + ih * 64 + ty * 4 + r;
#pragma unroll
            for (int jh = 0; jh < 2; jh++) {
                int col = bn * 128 + jh * 64 + tx * 4;
                float4 bb = *(const float4*)(bias + col);
                float4 o;
                o.x = acc[ih * 4 + r][jh * 4 + 0] + bb.x;
                o.y = acc[ih * 4 + r][jh * 4 + 1] + bb.y;
                o.z = acc[ih * 4 + r][jh * 4 + 2] + bb.z;
                o.w = acc[ih * 4 + r][jh * 4 + 3] + bb.w;
                *(float4*)(C + (size_t)row * N + col) = o;
            }
        }
    }
}

// ---------------- 64x64 SGEMM + bias (for N=64 v_shared GEMM) ----------------
__global__ __launch_bounds__(256) void sgemm64(const float* __restrict__ A,
                                               const float* __restrict__ Bm,
                                               const float* __restrict__ bias,
                                               float* __restrict__ C,
                                               int M, int N, int K) {
    __shared__ float As[16][68];
    __shared__ float Bs[16][68];
    int tid = threadIdx.x;
    int bm = blockIdx.y, bn = blockIdx.x;
    int tx = tid & 15, ty = tid >> 4;
    int la_m = tid >> 2, la_k4 = (tid & 3) * 4;
    int lb_k = tid >> 4, lb_n4 = (tid & 15) * 4;

    float acc[4][4];
#pragma unroll
    for (int i = 0; i < 4; i++)
#pragma unroll
        for (int j = 0; j < 4; j++) acc[i][j] = 0.f;

    for (int k0 = 0; k0 < K; k0 += 16) {
        float4 a4 = *(const float4*)(A + (size_t)(bm * 64 + la_m) * K + k0 + la_k4);
        float4 b4 = *(const float4*)(Bm + (size_t)(k0 + lb_k) * N + bn * 64 + lb_n4);
        __syncthreads();
        As[la_k4 + 0][la_m] = a4.x;
        As[la_k4 + 1][la_m] = a4.y;
        As[la_k4 + 2][la_m] = a4.z;
        As[la_k4 + 3][la_m] = a4.w;
        *(float4*)&Bs[lb_k][lb_n4] = b4;
        __syncthreads();
#pragma unroll
        for (int kk = 0; kk < 16; kk++) {
            float4 a0 = *(float4*)&As[kk][ty * 4];
            float4 b0 = *(float4*)&Bs[kk][tx * 4];
            float av[4] = {a0.x, a0.y, a0.z, a0.w};
            float bw[4] = {b0.x, b0.y, b0.z, b0.w};
#pragma unroll
            for (int i = 0; i < 4; i++)
#pragma unroll
                for (int j = 0; j < 4; j++) acc[i][j] += av[i] * bw[j];
        }
    }
#pragma unroll
    for (int r = 0; r < 4; r++) {
        int row = bm * 64 + ty * 4 + r;
        int col = bn * 64 + tx * 4;
        float4 bb = *(const float4*)(bias + col);
        float4 o;
        o.x = acc[r][0] + bb.x;
        o.y = acc[r][1] + bb.y;
        o.z = acc[r][2] + bb.z;
        o.w = acc[r][3] + bb.w;
        *(float4*)(C + (size_t)row * N + col) = o;
    }
}

// ---------------- fused attention: logits -> sparsemax -> avg -> PV ----------------
// block = 256 thr, grid = 512 (one block per (b, 8-query tile)); 16 heads looped inside.
// LDS: L[8][1024] logits/probs (32KB) + KV[128][64] xor-swizzled K/V tile (32KB) = 64KB.
#define LSTR 1024
__global__ __launch_bounds__(256) void attn_kernel(const float* __restrict__ qm,
                                                   const float* __restrict__ km,
                                                   const float* __restrict__ vsh,
                                                   float* __restrict__ ocat,
                                                   float* __restrict__ avg) {
    __shared__ float L[8 * LSTR];
    __shared__ float KV[128 * 64];

    int tid = threadIdx.x;
    int bb = blockIdx.x >> 7;       // batch
    int qt = blockIdx.x & 127;      // q-tile within batch
    int row0 = bb * S_ + qt * 8;    // first global row (of 4096)

    // logits mapping: wave-uniform row pair + per-lane key
    int rowg = tid >> 6;            // 0..3 -> rows rowg*2, rowg*2+1
    int kg = tid & 63;              // key within half-tile
    // sparsemax mapping
    int si = tid >> 5, sl = tid & 31;
    // PV mapping
    int rg = tid >> 7;              // 0..1 -> rows rg*4..rg*4+3
    int seg = (tid >> 4) & 7;       // kk-split
    int jg = tid & 15;              // col quad

    for (int h = 0; h < H_; h++) {
        // ---- Q rows into registers (broadcast loads, wave-uniform rows) ----
        float4 qa[16], qb[16];
        {
            const float* q0 = qm + (size_t)(row0 + rowg * 2) * D_ + h * DH;
            const float* q1 = q0 + D_;
#pragma unroll
            for (int jq = 0; jq < 16; jq++) {
                qa[jq] = *(const float4*)(q0 + jq * 4);
                qb[jq] = *(const float4*)(q1 + jq * 4);
            }
        }
        // ---- logits over 8 key tiles of 128 ----
        for (int kt = 0; kt < 8; kt++) {
            __syncthreads();
#pragma unroll
            for (int m = 0; m < 8; m++) {
                int f4 = tid + 256 * m;
                int kk = f4 >> 4, jq = f4 & 15;
                float4 val = *(const float4*)(km + (size_t)(bb * S_ + kt * 128 + kk) * D_ + h * DH + jq * 4);
                *(float4*)&KV[kk * 64 + ((jq ^ (kk & 15)) << 2)] = val;
            }
            __syncthreads();
            float acc0 = 0.f, acc1 = 0.f, acc2 = 0.f, acc3 = 0.f;
#pragma unroll
            for (int jq = 0; jq < 16; jq++) {
                int sw = (jq ^ (kg & 15)) << 2;
                float4 k0v = *(float4*)&KV[kg * 64 + sw];
                float4 k1v = *(float4*)&KV[(kg + 64) * 64 + sw];  // (kg+64)&15 == kg&15
                acc0 += qa[jq].x * k0v.x + qa[jq].y * k0v.y + qa[jq].z * k0v.z + qa[jq].w * k0v.w;
                acc1 += qb[jq].x * k0v.x + qb[jq].y * k0v.y + qb[jq].z * k0v.z + qb[jq].w * k0v.w;
                acc2 += qa[jq].x * k1v.x + qa[jq].y * k1v.y + qa[jq].z * k1v.z + qa[jq].w * k1v.w;
                acc3 += qb[jq].x * k1v.x + qb[jq].y * k1v.y + qb[jq].z * k1v.z + qb[jq].w * k1v.w;
            }
            int i0 = rowg * 2;
            L[i0 * LSTR + kt * 128 + kg]            = acc0 * 0.125f;
            L[(i0 + 1) * LSTR + kt * 128 + kg]      = acc1 * 0.125f;
            L[i0 * LSTR + kt * 128 + 64 + kg]       = acc2 * 0.125f;
            L[(i0 + 1) * LSTR + kt * 128 + 64 + kg] = acc3 * 0.125f;
        }
        __syncthreads();
        // ---- sparsemax (Newton on tau), row si by 32 lanes; elems in registers ----
        {
            float* Lr = &L[si * LSTR];
            float4 zq[8];
#pragma unroll
            for (int qd = 0; qd < 8; qd++) zq[qd] = *(float4*)&Lr[(qd * 32 + sl) * 4];
            float mx = -3.0e38f;
#pragma unroll
            for (int qd = 0; qd < 8; qd++)
                mx = fmaxf(mx, fmaxf(fmaxf(zq[qd].x, zq[qd].y), fmaxf(zq[qd].z, zq[qd].w)));
#pragma unroll
            for (int off = 16; off >= 1; off >>= 1) mx = fmaxf(mx, __shfl_xor(mx, off, 32));

            float tau = mx - 1.0f;
            for (int it = 0; it < 64; it++) {
                float s = 0.f, cnt = 0.f;
#pragma unroll
                for (int qd = 0; qd < 8; qd++) {
                    if (zq[qd].x > tau) { s += zq[qd].x; cnt += 1.f; }
                    if (zq[qd].y > tau) { s += zq[qd].y; cnt += 1.f; }
                    if (zq[qd].z > tau) { s += zq[qd].z; cnt += 1.f; }
                    if (zq[qd].w > tau) { s += zq[qd].w; cnt += 1.f; }
                }
#pragma unroll
                for (int off = 16; off >= 1; off >>= 1) {
                    s += __shfl_xor(s, off, 32);
                    cnt += __shfl_xor(cnt, off, 32);
                }
                float tnew = (s - 1.f) / cnt;
                if (!(tnew > tau)) break;
                tau = tnew;
            }
            // write probs back + accumulate avg_attention (exclusive ownership, no atomics)
            float* avgp = avg + (size_t)(row0 + si) * S_;
#pragma unroll
            for (int qd = 0; qd < 8; qd++) {
                float4 p;
                p.x = fmaxf(zq[qd].x - tau, 0.f);
                p.y = fmaxf(zq[qd].y - tau, 0.f);
                p.z = fmaxf(zq[qd].z - tau, 0.f);
                p.w = fmaxf(zq[qd].w - tau, 0.f);
                *(float4*)&Lr[(qd * 32 + sl) * 4] = p;
                float4* dst = (float4*)(avgp + (qd * 32 + sl) * 4);
                float4 c4;
                c4.x = p.x * 0.0625f; c4.y = p.y * 0.0625f;
                c4.z = p.z * 0.0625f; c4.w = p.w * 0.0625f;
                if (h == 0) {
                    *dst = c4;
                } else {
                    float4 old = *dst;
                    old.x += c4.x; old.y += c4.y; old.z += c4.z; old.w += c4.w;
                    *dst = old;
                }
            }
        }
        // ---- PV: out[i][j] = sum_kk P[i][kk] * v_shared[kk][j] ----
        float pacc[4][4];
#pragma unroll
        for (int r = 0; r < 4; r++)
#pragma unroll
            for (int c = 0; c < 4; c++) pacc[r][c] = 0.f;

        for (int vt = 0; vt < 8; vt++) {
            __syncthreads();
#pragma unroll
            for (int m = 0; m < 8; m++) {
                int f4 = tid + 256 * m;
                int kk = f4 >> 4, jq = f4 & 15;
                float4 val = *(const float4*)(vsh + (size_t)(bb * S_ + vt * 128 + kk) * DH + jq * 4);
                *(float4*)&KV[kk * 64 + ((jq ^ (kk & 15)) << 2)] = val;
            }
            __syncthreads();
#pragma unroll
            for (int mq = 0; mq < 4; mq++) {
                int kk4 = (seg * 4 + mq) * 4;
                float lparr[4][4];
#pragma unroll
                for (int r = 0; r < 4; r++) {
                    float4 t = *(float4*)&L[(rg * 4 + r) * LSTR + vt * 128 + kk4];
                    lparr[r][0] = t.x; lparr[r][1] = t.y; lparr[r][2] = t.z; lparr[r][3] = t.w;
                }
#pragma unroll
                for (int c = 0; c < 4; c++) {
                    int kk = kk4 + c;
                    float4 vv = *(float4*)&KV[kk * 64 + ((jg ^ (kk & 15)) << 2)];
#pragma unroll
                    for (int r = 0; r < 4; r++) {
                        pacc[r][0] += lparr[r][c] * vv.x;
                        pacc[r][1] += lparr[r][c] * vv.y;
                        pacc[r][2] += lparr[r][c] * vv.z;
                        pacc[r][3] += lparr[r][c] * vv.w;
                    }
                }
            }
        }
        // ---- reduce 8 kk-segments via LDS (reuse KV), store out_cat ----
        __syncthreads();
        float* red = KV;
#pragma unroll
        for (int r = 0; r < 4; r++)
#pragma unroll
            for (int c = 0; c < 4; c++) red[tid * 17 + r * 4 + c] = pacc[r][c];
        __syncthreads();
        {
            int o0 = tid * 2;
            int i = o0 >> 6, j = o0 & 63;
            float2 ov;
            float s0 = 0.f, s1 = 0.f;
#pragma unroll
            for (int s2 = 0; s2 < 8; s2++) {
                int tsrc = ((i >> 2) << 7) | (s2 << 4) | (j >> 2);
                s0 += red[tsrc * 17 + (i & 3) * 4 + (j & 3)];
                s1 += red[tsrc * 17 + (i & 3) * 4 + ((j + 1) & 3)];
            }
            ov.x = s0; ov.y = s1;
            *(float2*)(ocat + (size_t)(row0 + i) * D_ + h * DH + j) = ov;
        }
    }
}

extern "C" void kernel_launch(void* const* d_in, const int* in_sizes, int n_in,
                              void* d_out, int out_size, void* d_ws, size_t ws_size,
                              hipStream_t stream) {
    const float* x  = (const float*)d_in[0];
    const float* Wq = (const float*)d_in[1];
    const float* bq = (const float*)d_in[2];
    const float* Wk = (const float*)d_in[3];
    const float* bk = (const float*)d_in[4];
    const float* Wv = (const float*)d_in[5];
    const float* bv = (const float*)d_in[6];
    const float* Wo = (const float*)d_in[7];
    const float* bo = (const float*)d_in[8];

    float* xout = (float*)d_out;                       // (B,S,D) = 4M floats
    float* avg  = xout + (size_t)BS * D_;              // (B,S,S) = 4M floats

    float* ws   = (float*)d_ws;
    float* qb   = ws;                                  // 4M
    float* kb   = qb + (size_t)BS * D_;                // 4M
    float* vshb = kb + (size_t)BS * D_;                // 256K
    float* ocat = vshb + (size_t)BS * DH;              // 4M
    float* Wvsh = ocat + (size_t)BS * D_;              // 64K
    float* bvsh = Wvsh + (size_t)D_ * DH;              // 64

    wv_reduce_kernel<<<256, 256, 0, stream>>>(Wv, bv, Wvsh, bvsh);
    sgemm128<<<dim3(D_ / 128, BS / 128), 256, 0, stream>>>(x, Wq, bq, qb, BS, D_, D_);
    sgemm128<<<dim3(D_ / 128, BS / 128), 256, 0, stream>>>(x, Wk, bk, kb, BS, D_, D_);
    sgemm64<<<dim3(1, BS / 64), 256, 0, stream>>>(x, Wvsh, bvsh, vshb, BS, DH, D_);
    attn_kernel<<<512, 256, 0, stream>>>(qb, kb, vshb, ocat, avg);
    sgemm128<<<dim3(D_ / 128, BS / 128), 256, 0, stream>>>(ocat, Wo, bo, xout, BS, D_, D_);
}

// Round 2
// 1481.993 us; speedup vs baseline: 1.3003x; 1.3003x over previous
//
#include <hip/hip_runtime.h>

#define B_  4
#define S_  1024
#define D_  1024
#define H_  16
#define DH  64
#define BS  4096   // B_*S_
#define LPAD 68    // padded row stride (floats) for 64-wide LDS tiles

// ---------------- zero fill (avg buffer is poisoned 0xAA) ----------------
__global__ void zero_kernel(float* __restrict__ p, int n4) {
    int i = blockIdx.x * 256 + threadIdx.x;
    float4 z = {0.f, 0.f, 0.f, 0.f};
    for (; i < n4; i += gridDim.x * 256) ((float4*)p)[i] = z;
}

// ---------------- Wv head-mean reduction ----------------
__global__ void wv_reduce_kernel(const float* __restrict__ Wv, const float* __restrict__ bv,
                                 float* __restrict__ Wvsh, float* __restrict__ bvsh) {
    int e = blockIdx.x * 256 + threadIdx.x;
    if (e < D_ * DH) {
        int d = e >> 6, j = e & 63;
        float s = 0.f;
#pragma unroll
        for (int h = 0; h < H_; h++) s += Wv[d * D_ + h * DH + j];
        Wvsh[e] = s * (1.f / 16.f);
    }
    if (e < DH) {
        float s = 0.f;
#pragma unroll
        for (int h = 0; h < H_; h++) s += bv[h * DH + e];
        bvsh[e] = s * (1.f / 16.f);
    }
}

// ---------------- 128x128 SGEMM + bias (8x8 micro-tile) ----------------
__global__ __launch_bounds__(256) void sgemm128(const float* __restrict__ A,
                                                const float* __restrict__ Bm,
                                                const float* __restrict__ bias,
                                                float* __restrict__ C,
                                                int M, int N, int K) {
    __shared__ float As[8][128];
    __shared__ float Bs[8][128];
    int tid = threadIdx.x;
    int bm = blockIdx.y, bn = blockIdx.x;
    int tx = tid & 15, ty = tid >> 4;
    int arow = tid >> 1, acol4 = (tid & 1) * 4;
    int brow = tid >> 5, bcol4 = (tid & 31) * 4;

    float acc[8][8];
#pragma unroll
    for (int i = 0; i < 8; i++)
#pragma unroll
        for (int j = 0; j < 8; j++) acc[i][j] = 0.f;

    const float* Aptr = A + (size_t)(bm * 128 + arow) * K + acol4;
    const float* Bptr = Bm + (size_t)brow * N + bn * 128 + bcol4;

    for (int k0 = 0; k0 < K; k0 += 8) {
        float4 a4 = *(const float4*)(Aptr + k0);
        float4 b4 = *(const float4*)(Bptr + (size_t)k0 * N);
        __syncthreads();
        As[acol4 + 0][arow] = a4.x;
        As[acol4 + 1][arow] = a4.y;
        As[acol4 + 2][arow] = a4.z;
        As[acol4 + 3][arow] = a4.w;
        *(float4*)&Bs[brow][bcol4] = b4;
        __syncthreads();
#pragma unroll
        for (int kk = 0; kk < 8; kk++) {
            float4 a0 = *(float4*)&As[kk][ty * 4];
            float4 a1 = *(float4*)&As[kk][64 + ty * 4];
            float4 b0 = *(float4*)&Bs[kk][tx * 4];
            float4 b1 = *(float4*)&Bs[kk][64 + tx * 4];
            float av[8] = {a0.x, a0.y, a0.z, a0.w, a1.x, a1.y, a1.z, a1.w};
            float bw[8] = {b0.x, b0.y, b0.z, b0.w, b1.x, b1.y, b1.z, b1.w};
#pragma unroll
            for (int i = 0; i < 8; i++)
#pragma unroll
                for (int j = 0; j < 8; j++) acc[i][j] += av[i] * bw[j];
        }
    }
#pragma unroll
    for (int ih = 0; ih < 2; ih++) {
#pragma unroll
        for (int r = 0; r < 4; r++) {
            int row = bm * 128 + ih * 64 + ty * 4 + r;
#pragma unroll
            for (int jh = 0; jh < 2; jh++) {
                int col = bn * 128 + jh * 64 + tx * 4;
                float4 bb = *(const float4*)(bias + col);
                float4 o;
                o.x = acc[ih * 4 + r][jh * 4 + 0] + bb.x;
                o.y = acc[ih * 4 + r][jh * 4 + 1] + bb.y;
                o.z = acc[ih * 4 + r][jh * 4 + 2] + bb.z;
                o.w = acc[ih * 4 + r][jh * 4 + 3] + bb.w;
                *(float4*)(C + (size_t)row * N + col) = o;
            }
        }
    }
}

// ---------------- 64x64 SGEMM + bias (for N=64 v_shared GEMM) ----------------
__global__ __launch_bounds__(256) void sgemm64(const float* __restrict__ A,
                                               const float* __restrict__ Bm,
                                               const float* __restrict__ bias,
                                               float* __restrict__ C,
                                               int M, int N, int K) {
    __shared__ float As[16][68];
    __shared__ float Bs[16][68];
    int tid = threadIdx.x;
    int bm = blockIdx.y, bn = blockIdx.x;
    int tx = tid & 15, ty = tid >> 4;
    int la_m = tid >> 2, la_k4 = (tid & 3) * 4;
    int lb_k = tid >> 4, lb_n4 = (tid & 15) * 4;

    float acc[4][4];
#pragma unroll
    for (int i = 0; i < 4; i++)
#pragma unroll
        for (int j = 0; j < 4; j++) acc[i][j] = 0.f;

    for (int k0 = 0; k0 < K; k0 += 16) {
        float4 a4 = *(const float4*)(A + (size_t)(bm * 64 + la_m) * K + k0 + la_k4);
        float4 b4 = *(const float4*)(Bm + (size_t)(k0 + lb_k) * N + bn * 64 + lb_n4);
        __syncthreads();
        As[la_k4 + 0][la_m] = a4.x;
        As[la_k4 + 1][la_m] = a4.y;
        As[la_k4 + 2][la_m] = a4.z;
        As[la_k4 + 3][la_m] = a4.w;
        *(float4*)&Bs[lb_k][lb_n4] = b4;
        __syncthreads();
#pragma unroll
        for (int kk = 0; kk < 16; kk++) {
            float4 a0 = *(float4*)&As[kk][ty * 4];
            float4 b0 = *(float4*)&Bs[kk][tx * 4];
            float av[4] = {a0.x, a0.y, a0.z, a0.w};
            float bw[4] = {b0.x, b0.y, b0.z, b0.w};
#pragma unroll
            for (int i = 0; i < 4; i++)
#pragma unroll
                for (int j = 0; j < 4; j++) acc[i][j] += av[i] * bw[j];
        }
    }
#pragma unroll
    for (int r = 0; r < 4; r++) {
        int row = bm * 64 + ty * 4 + r;
        int col = bn * 64 + tx * 4;
        float4 bb = *(const float4*)(bias + col);
        float4 o;
        o.x = acc[r][0] + bb.x;
        o.y = acc[r][1] + bb.y;
        o.z = acc[r][2] + bb.z;
        o.w = acc[r][3] + bb.w;
        *(float4*)(C + (size_t)row * N + col) = o;
    }
}

// ---------------- attention v2: one (b, head, 16-q-row) tile per block ----------------
// grid = 4096, 256 threads. Logits in registers (64/lane, 16 lanes per row).
// K tiles through padded LDS. Sparsemax via width-16 shuffles. avg via sparse
// atomics (support ~4/1024). PV via sparse direct-global V reads (L2-resident).
__global__ __launch_bounds__(256) void attn2(const float* __restrict__ qm,
                                             const float* __restrict__ km,
                                             const float* __restrict__ vsh,
                                             float* __restrict__ ocat,
                                             float* __restrict__ avg) {
    __shared__ float KT[128 * LPAD];

    int tid = threadIdx.x;
    int qt = blockIdx.x & 63;
    int h  = (blockIdx.x >> 6) & 15;
    int bb = blockIdx.x >> 10;
    int row0 = bb * S_ + qt * 16;
    int r = tid >> 4, c = tid & 15;

    // Q row into registers (16-way duplicated read, L1/L2-served)
    float4 qreg[16];
    {
        const float* qp = qm + (size_t)(row0 + r) * D_ + h * DH;
#pragma unroll
        for (int j = 0; j < 16; j++) qreg[j] = *(const float4*)(qp + 4 * j);
    }

    float pval[64];   // lane (r,c) owns logits of row r at keys c+16u

    for (int kt = 0; kt < 8; kt++) {
        __syncthreads();
#pragma unroll
        for (int m = 0; m < 8; m++) {
            int idx = tid + 256 * m;
            int kk = idx >> 4, jq = idx & 15;
            float4 v = *(const float4*)(km + (size_t)(bb * S_ + kt * 128 + kk) * D_ + h * DH + 4 * jq);
            *(float4*)&KT[kk * LPAD + 4 * jq] = v;
        }
        __syncthreads();
#pragma unroll
        for (int u = 0; u < 8; u++) {
            int kk = c + 16 * u;
            float acc = 0.f;
#pragma unroll
            for (int j = 0; j < 16; j++) {
                float4 kv = *(float4*)&KT[kk * LPAD + 4 * j];
                acc += qreg[j].x * kv.x + qreg[j].y * kv.y + qreg[j].z * kv.z + qreg[j].w * kv.w;
            }
            pval[kt * 8 + u] = acc * 0.125f;
        }
    }

    // ---- sparsemax (Newton on tau) across the 16 c-lanes of row r ----
    float mx = -3.0e38f;
#pragma unroll
    for (int u = 0; u < 64; u++) mx = fmaxf(mx, pval[u]);
#pragma unroll
    for (int off = 8; off >= 1; off >>= 1) mx = fmaxf(mx, __shfl_xor(mx, off, 16));

    float tau = mx - 1.0f;
    for (int it = 0; it < 32; it++) {
        float s = 0.f, cnt = 0.f;
#pragma unroll
        for (int u = 0; u < 64; u++) {
            if (pval[u] > tau) { s += pval[u]; cnt += 1.f; }
        }
#pragma unroll
        for (int off = 8; off >= 1; off >>= 1) {
            s += __shfl_xor(s, off, 16);
            cnt += __shfl_xor(cnt, off, 16);
        }
        float tnew = (s - 1.f) / cnt;
        if (!(tnew > tau)) break;
        tau = tnew;
    }

    // ---- probs, nonzero mask, sparse avg atomics ----
    unsigned long long nzm = 0ull;
    float* avgp = avg + (size_t)(row0 + r) * S_;
#pragma unroll
    for (int u = 0; u < 64; u++) {
        float p = fmaxf(pval[u] - tau, 0.f);
        pval[u] = p;
        if (p > 0.f) {
            nzm |= (1ull << u);
            atomicAdd(avgp + c + 16 * u, p * 0.0625f);
        }
    }

    // ---- PV: sparse walk of nonzeros, V rows direct from global (L2-hot) ----
    float4 acc[16];
#pragma unroll
    for (int t = 0; t < 16; t++) acc[t] = make_float4(0.f, 0.f, 0.f, 0.f);
    const float* vb = vsh + (size_t)bb * S_ * DH;
    while (__any(nzm != 0ull)) {
        if (nzm) {
            int u = __builtin_ctzll(nzm);
            nzm &= nzm - 1;
            float p = pval[u];
            const float* vr = vb + (size_t)(c + 16 * u) * DH;
#pragma unroll
            for (int t = 0; t < 16; t++) {
                float4 vv = *(const float4*)(vr + 4 * t);
                acc[t].x += p * vv.x;
                acc[t].y += p * vv.y;
                acc[t].z += p * vv.z;
                acc[t].w += p * vv.w;
            }
        }
    }
    // butterfly-reduce across the 16 c-lanes of each row
#pragma unroll
    for (int off = 8; off >= 1; off >>= 1) {
#pragma unroll
        for (int t = 0; t < 16; t++) {
            acc[t].x += __shfl_xor(acc[t].x, off, 16);
            acc[t].y += __shfl_xor(acc[t].y, off, 16);
            acc[t].z += __shfl_xor(acc[t].z, off, 16);
            acc[t].w += __shfl_xor(acc[t].w, off, 16);
        }
    }
    *(float4*)(ocat + (size_t)(row0 + r) * D_ + h * DH + 4 * c) = acc[c];
}

extern "C" void kernel_launch(void* const* d_in, const int* in_sizes, int n_in,
                              void* d_out, int out_size, void* d_ws, size_t ws_size,
                              hipStream_t stream) {
    const float* x  = (const float*)d_in[0];
    const float* Wq = (const float*)d_in[1];
    const float* bq = (const float*)d_in[2];
    const float* Wk = (const float*)d_in[3];
    const float* bk = (const float*)d_in[4];
    const float* Wv = (const float*)d_in[5];
    const float* bv = (const float*)d_in[6];
    const float* Wo = (const float*)d_in[7];
    const float* bo = (const float*)d_in[8];

    float* xout = (float*)d_out;                       // (B,S,D)
    float* avg  = xout + (size_t)BS * D_;              // (B,S,S)

    float* ws   = (float*)d_ws;
    float* qb   = ws;                                  // 4M
    float* kb   = qb + (size_t)BS * D_;                // 4M
    float* vshb = kb + (size_t)BS * D_;                // 256K
    float* ocat = vshb + (size_t)BS * DH;              // 4M
    float* Wvsh = ocat + (size_t)BS * D_;              // 64K
    float* bvsh = Wvsh + (size_t)D_ * DH;              // 64

    zero_kernel<<<4096, 256, 0, stream>>>(avg, BS * S_ / 4);
    wv_reduce_kernel<<<256, 256, 0, stream>>>(Wv, bv, Wvsh, bvsh);
    sgemm128<<<dim3(D_ / 128, BS / 128), 256, 0, stream>>>(x, Wq, bq, qb, BS, D_, D_);
    sgemm128<<<dim3(D_ / 128, BS / 128), 256, 0, stream>>>(x, Wk, bk, kb, BS, D_, D_);
    sgemm64<<<dim3(1, BS / 64), 256, 0, stream>>>(x, Wvsh, bvsh, vshb, BS, DH, D_);
    attn2<<<4096, 256, 0, stream>>>(qb, kb, vshb, ocat, avg);
    sgemm128<<<dim3(D_ / 128, BS / 128), 256, 0, stream>>>(ocat, Wo, bo, xout, BS, D_, D_);
}

// Round 3
// 722.844 us; speedup vs baseline: 2.6660x; 2.0502x over previous
//
#include <hip/hip_runtime.h>

#define B_  4
#define S_  1024
#define D_  1024
#define H_  16
#define DH  64
#define BS  4096   // B_*S_

typedef __bf16 bf16x8 __attribute__((ext_vector_type(8)));
typedef float  f32x4  __attribute__((ext_vector_type(4)));

__device__ __forceinline__ unsigned short f2bf(float f) {
    __bf16 b = (__bf16)f;
    return __builtin_bit_cast(unsigned short, b);
}
__device__ __forceinline__ float bf2f(unsigned short u) {
    return (float)__builtin_bit_cast(__bf16, u);
}

// ---------------- Wv head-mean reduction (fp32) ----------------
__global__ void wv_reduce_kernel(const float* __restrict__ Wv, const float* __restrict__ bv,
                                 float* __restrict__ Wvsh, float* __restrict__ bvsh) {
    int e = blockIdx.x * 256 + threadIdx.x;
    if (e < D_ * DH) {
        int d = e >> 6, j = e & 63;
        float s = 0.f;
#pragma unroll
        for (int h = 0; h < H_; h++) s += Wv[d * D_ + h * DH + j];
        Wvsh[e] = s * (1.f / 16.f);
    }
    if (e < DH) {
        float s = 0.f;
#pragma unroll
        for (int h = 0; h < H_; h++) s += bv[h * DH + e];
        bvsh[e] = s * (1.f / 16.f);
    }
}

// ---------------- 64x64 fp32 SGEMM + bias (v_shared, N=64) ----------------
__global__ __launch_bounds__(256) void sgemm64(const float* __restrict__ A,
                                               const float* __restrict__ Bm,
                                               const float* __restrict__ bias,
                                               float* __restrict__ C,
                                               int M, int N, int K) {
    __shared__ float As[16][68];
    __shared__ float Bs[16][68];
    int tid = threadIdx.x;
    int bm = blockIdx.y, bn = blockIdx.x;
    int tx = tid & 15, ty = tid >> 4;
    int la_m = tid >> 2, la_k4 = (tid & 3) * 4;
    int lb_k = tid >> 4, lb_n4 = (tid & 15) * 4;

    float acc[4][4];
#pragma unroll
    for (int i = 0; i < 4; i++)
#pragma unroll
        for (int j = 0; j < 4; j++) acc[i][j] = 0.f;

    for (int k0 = 0; k0 < K; k0 += 16) {
        float4 a4 = *(const float4*)(A + (size_t)(bm * 64 + la_m) * K + k0 + la_k4);
        float4 b4 = *(const float4*)(Bm + (size_t)(k0 + lb_k) * N + bn * 64 + lb_n4);
        __syncthreads();
        As[la_k4 + 0][la_m] = a4.x;
        As[la_k4 + 1][la_m] = a4.y;
        As[la_k4 + 2][la_m] = a4.z;
        As[la_k4 + 3][la_m] = a4.w;
        *(float4*)&Bs[lb_k][lb_n4] = b4;
        __syncthreads();
#pragma unroll
        for (int kk = 0; kk < 16; kk++) {
            float4 a0 = *(float4*)&As[kk][ty * 4];
            float4 b0 = *(float4*)&Bs[kk][tx * 4];
            float av[4] = {a0.x, a0.y, a0.z, a0.w};
            float bw[4] = {b0.x, b0.y, b0.z, b0.w};
#pragma unroll
            for (int i = 0; i < 4; i++)
#pragma unroll
                for (int j = 0; j < 4; j++) acc[i][j] += av[i] * bw[j];
        }
    }
#pragma unroll
    for (int r = 0; r < 4; r++) {
        int row = bm * 64 + ty * 4 + r;
        int col = bn * 64 + tx * 4;
        float4 bb = *(const float4*)(bias + col);
        float4 o;
        o.x = acc[r][0] + bb.x;
        o.y = acc[r][1] + bb.y;
        o.z = acc[r][2] + bb.z;
        o.w = acc[r][3] + bb.w;
        *(float4*)(C + (size_t)row * N + col) = o;
    }
}

// ---------------- transpose + bf16 hi/lo split of a DxD weight ----------------
// Th[n][k] = bf16(W[k][n]); Tl = bf16 residual (if wantLo)
__global__ __launch_bounds__(256) void wTsplit(const float* __restrict__ W,
                                               unsigned short* __restrict__ Th,
                                               unsigned short* __restrict__ Tl,
                                               int wantLo) {
    __shared__ float tile[32][33];
    int tid = threadIdx.x;
    int tn = blockIdx.x & 31, tk = blockIdx.x >> 5;
    int r = tid >> 3, c4 = (tid & 7) * 4;
    float4 v = *(const float4*)(W + (size_t)(tk * 32 + r) * D_ + tn * 32 + c4);
    tile[r][c4 + 0] = v.x;
    tile[r][c4 + 1] = v.y;
    tile[r][c4 + 2] = v.z;
    tile[r][c4 + 3] = v.w;
    __syncthreads();
    unsigned short hh[4], ll[4];
#pragma unroll
    for (int i = 0; i < 4; i++) {
        float f = tile[c4 + i][r];
        hh[i] = f2bf(f);
        ll[i] = f2bf(f - bf2f(hh[i]));
    }
    size_t off = (size_t)(tn * 32 + r) * D_ + tk * 32 + c4;
    *(uint2*)(Th + off) = make_uint2((unsigned)hh[0] | ((unsigned)hh[1] << 16),
                                     (unsigned)hh[2] | ((unsigned)hh[3] << 16));
    if (wantLo)
        *(uint2*)(Tl + off) = make_uint2((unsigned)ll[0] | ((unsigned)ll[1] << 16),
                                         (unsigned)ll[2] | ((unsigned)ll[3] << 16));
}

// ---------------- bf16 MFMA GEMM, 128x64 tile, B^T layout ----------------
// HILO=1: A = fp32 (split hi/lo on the fly), C = A@(Bh+Bl) via 3 products,
//         out = bf16 hi/lo pair (Ch, Cl).
// HILO=0: A = bf16, 1 product, out = fp32 Cf.
template<int HILO, int OUTMODE>
__global__ __launch_bounds__(256) void bgemm(const float* __restrict__ Afp,
                                             const unsigned short* __restrict__ Abf,
                                             const unsigned short* __restrict__ Bh,
                                             const unsigned short* __restrict__ Bl,
                                             const float* __restrict__ bias,
                                             float* __restrict__ Cf,
                                             unsigned short* __restrict__ Ch,
                                             unsigned short* __restrict__ Cl) {
    __shared__ unsigned short AhS[128 * 32];
    __shared__ unsigned short AlS[HILO ? 128 * 32 : 8];
    __shared__ unsigned short BhS[64 * 32];
    __shared__ unsigned short BlS[HILO ? 64 * 32 : 8];

    int tid = threadIdx.x;
    int bn = blockIdx.x, bm = blockIdx.y;
    int w = tid >> 6, lane = tid & 63;
    int m16 = lane & 15, qd = lane >> 4;
    int rh = (w >> 1) * 64, ch = (w & 1) * 32;

    f32x4 acc[4][2];
#pragma unroll
    for (int it = 0; it < 4; it++)
#pragma unroll
        for (int jt = 0; jt < 2; jt++) acc[it][jt] = (f32x4){0.f, 0.f, 0.f, 0.f};

    for (int k0 = 0; k0 < D_; k0 += 32) {
        __syncthreads();
        if (HILO) {
#pragma unroll
            for (int i = 0; i < 2; i++) {
                int idx = i * 256 + tid;
                int row = idx >> 2, seg = idx & 3;
                const float* src = Afp + (size_t)(bm * 128 + row) * D_ + k0 + seg * 8;
                float4 v0 = *(const float4*)src;
                float4 v1 = *(const float4*)(src + 4);
                float vv[8] = {v0.x, v0.y, v0.z, v0.w, v1.x, v1.y, v1.z, v1.w};
                unsigned int hw[4], lw[4];
#pragma unroll
                for (int j = 0; j < 4; j++) {
                    unsigned short h0 = f2bf(vv[2 * j]), h1 = f2bf(vv[2 * j + 1]);
                    unsigned short l0 = f2bf(vv[2 * j] - bf2f(h0));
                    unsigned short l1 = f2bf(vv[2 * j + 1] - bf2f(h1));
                    hw[j] = (unsigned)h0 | ((unsigned)h1 << 16);
                    lw[j] = (unsigned)l0 | ((unsigned)l1 << 16);
                }
                *(uint4*)((char*)AhS + idx * 16) = make_uint4(hw[0], hw[1], hw[2], hw[3]);
                *(uint4*)((char*)AlS + idx * 16) = make_uint4(lw[0], lw[1], lw[2], lw[3]);
            }
        } else {
#pragma unroll
            for (int i = 0; i < 2; i++) {
                int idx = i * 256 + tid;
                int row = idx >> 2, seg = idx & 3;
                uint4 v = *(const uint4*)(Abf + (size_t)(bm * 128 + row) * D_ + k0 + seg * 8);
                *(uint4*)((char*)AhS + idx * 16) = v;
            }
        }
        {
            int row = tid >> 2, seg = tid & 3;
            uint4 v = *(const uint4*)(Bh + (size_t)(bn * 64 + row) * D_ + k0 + seg * 8);
            *(uint4*)((char*)BhS + tid * 16) = v;
            if (HILO) {
                uint4 v2 = *(const uint4*)(Bl + (size_t)(bn * 64 + row) * D_ + k0 + seg * 8);
                *(uint4*)((char*)BlS + tid * 16) = v2;
            }
        }
        __syncthreads();
        bf16x8 ah[4], al[4], bh2[2], bl2[2];
#pragma unroll
        for (int it = 0; it < 4; it++) {
            ah[it] = *(const bf16x8*)((char*)AhS + (rh + it * 16 + m16) * 64 + qd * 16);
            if (HILO) al[it] = *(const bf16x8*)((char*)AlS + (rh + it * 16 + m16) * 64 + qd * 16);
        }
#pragma unroll
        for (int jt = 0; jt < 2; jt++) {
            bh2[jt] = *(const bf16x8*)((char*)BhS + (ch + jt * 16 + m16) * 64 + qd * 16);
            if (HILO) bl2[jt] = *(const bf16x8*)((char*)BlS + (ch + jt * 16 + m16) * 64 + qd * 16);
        }
#pragma unroll
        for (int it = 0; it < 4; it++)
#pragma unroll
            for (int jt = 0; jt < 2; jt++) {
                acc[it][jt] = __builtin_amdgcn_mfma_f32_16x16x32_bf16(ah[it], bh2[jt], acc[it][jt], 0, 0, 0);
                if (HILO) {
                    acc[it][jt] = __builtin_amdgcn_mfma_f32_16x16x32_bf16(ah[it], bl2[jt], acc[it][jt], 0, 0, 0);
                    acc[it][jt] = __builtin_amdgcn_mfma_f32_16x16x32_bf16(al[it], bh2[jt], acc[it][jt], 0, 0, 0);
                }
            }
    }
#pragma unroll
    for (int it = 0; it < 4; it++)
#pragma unroll
        for (int jt = 0; jt < 2; jt++)
#pragma unroll
            for (int r = 0; r < 4; r++) {
                int R = bm * 128 + rh + it * 16 + qd * 4 + r;
                int Cc = bn * 64 + ch + jt * 16 + m16;
                float v = acc[it][jt][r] + bias[Cc];
                if (OUTMODE == 0) {
                    Cf[(size_t)R * D_ + Cc] = v;
                } else {
                    unsigned short h0 = f2bf(v);
                    Ch[(size_t)R * D_ + Cc] = h0;
                    Cl[(size_t)R * D_ + Cc] = f2bf(v - bf2f(h0));
                }
            }
}

// ---------------- fused attention: MFMA hi/lo logits -> sparsemax -> slots -> PV ----------------
// grid 4096 = (b, h, 16-row q-tile); 256 thr = 4 waves; wave w covers keys [w*256, w*256+256).
// K/Q frags loaded straight from global (L2-hot), logits live in C-fragments only.
__global__ __launch_bounds__(256) void attn4(const unsigned short* __restrict__ qh,
                                             const unsigned short* __restrict__ ql,
                                             const unsigned short* __restrict__ kh,
                                             const unsigned short* __restrict__ kl,
                                             const float* __restrict__ vsh,
                                             unsigned short* __restrict__ och,
                                             unsigned short* __restrict__ sidx,
                                             unsigned short* __restrict__ sval,
                                             int* __restrict__ scnt) {
    __shared__ float smS[4][16], smC[4][16], smM[4][16];
    __shared__ int cnt16[16];
    __shared__ int slotI[16][16];
    __shared__ float slotV[16][16];

    int tid = threadIdx.x, w = tid >> 6, lane = tid & 63;
    int qt = blockIdx.x & 63, h = (blockIdx.x >> 6) & 15, bb = blockIdx.x >> 10;
    int row0g = bb * S_ + qt * 16;
    int kbase = bb * S_;
    int m16 = lane & 15, qd = lane >> 4;

    // Q A-frags (rows row0g+m16), k-chunks 0/1, hi+lo
    bf16x8 aH[2], aL[2];
#pragma unroll
    for (int c = 0; c < 2; c++) {
        size_t off = (size_t)(row0g + m16) * D_ + h * DH + c * 32 + qd * 8;
        aH[c] = *(const bf16x8*)(qh + off);
        aL[c] = *(const bf16x8*)(ql + off);
    }

    f32x4 Cfr[16];
#pragma unroll
    for (int t = 0; t < 16; t++) Cfr[t] = (f32x4){0.f, 0.f, 0.f, 0.f};

#pragma unroll 4
    for (int t = 0; t < 16; t++) {
        int n0 = w * 256 + t * 16;
        bf16x8 bH[2], bL[2];
#pragma unroll
        for (int c = 0; c < 2; c++) {
            size_t boff = (size_t)(kbase + n0 + m16) * D_ + h * DH + c * 32 + qd * 8;
            bH[c] = *(const bf16x8*)(kh + boff);
            bL[c] = *(const bf16x8*)(kl + boff);
        }
        f32x4 a = Cfr[t];
        a = __builtin_amdgcn_mfma_f32_16x16x32_bf16(aH[0], bH[0], a, 0, 0, 0);
        a = __builtin_amdgcn_mfma_f32_16x16x32_bf16(aH[1], bH[1], a, 0, 0, 0);
        a = __builtin_amdgcn_mfma_f32_16x16x32_bf16(aH[0], bL[0], a, 0, 0, 0);
        a = __builtin_amdgcn_mfma_f32_16x16x32_bf16(aH[1], bL[1], a, 0, 0, 0);
        a = __builtin_amdgcn_mfma_f32_16x16x32_bf16(aL[0], bH[0], a, 0, 0, 0);
        a = __builtin_amdgcn_mfma_f32_16x16x32_bf16(aL[1], bH[1], a, 0, 0, 0);
        Cfr[t] = a;
    }
#pragma unroll
    for (int t = 0; t < 16; t++)
#pragma unroll
        for (int r = 0; r < 4; r++) Cfr[t][r] *= 0.125f;

    // ---- max per row (rows qd*4+r, columns across 16 m-lanes x 4 waves) ----
    float mxr[4];
#pragma unroll
    for (int r = 0; r < 4; r++) mxr[r] = -3.0e38f;
#pragma unroll
    for (int t = 0; t < 16; t++)
#pragma unroll
        for (int r = 0; r < 4; r++) mxr[r] = fmaxf(mxr[r], Cfr[t][r]);
#pragma unroll
    for (int off = 8; off >= 1; off >>= 1)
#pragma unroll
        for (int r = 0; r < 4; r++) mxr[r] = fmaxf(mxr[r], __shfl_xor(mxr[r], off, 16));
    if (m16 == 0)
#pragma unroll
        for (int r = 0; r < 4; r++) smM[w][qd * 4 + r] = mxr[r];
    __syncthreads();
    float tau[4];
#pragma unroll
    for (int r = 0; r < 4; r++) {
        int row = qd * 4 + r;
        float mm = fmaxf(fmaxf(smM[0][row], smM[1][row]), fmaxf(smM[2][row], smM[3][row]));
        tau[r] = mm - 1.0f;
    }

    // ---- Newton on tau, block-lockstep with early exit ----
    for (int it = 0; it < 32; it++) {
        float s[4], c[4];
#pragma unroll
        for (int r = 0; r < 4; r++) { s[r] = 0.f; c[r] = 0.f; }
#pragma unroll
        for (int t = 0; t < 16; t++)
#pragma unroll
            for (int r = 0; r < 4; r++) {
                float z = Cfr[t][r];
                if (z > tau[r]) { s[r] += z; c[r] += 1.f; }
            }
#pragma unroll
        for (int off = 8; off >= 1; off >>= 1)
#pragma unroll
            for (int r = 0; r < 4; r++) {
                s[r] += __shfl_xor(s[r], off, 16);
                c[r] += __shfl_xor(c[r], off, 16);
            }
        __syncthreads();
        if (m16 == 0)
#pragma unroll
            for (int r = 0; r < 4; r++) {
                smS[w][qd * 4 + r] = s[r];
                smC[w][qd * 4 + r] = c[r];
            }
        __syncthreads();
        int done = 1;
#pragma unroll
        for (int r = 0; r < 4; r++) {
            int row = qd * 4 + r;
            float S = smS[0][row] + smS[1][row] + smS[2][row] + smS[3][row];
            float C = smC[0][row] + smC[1][row] + smC[2][row] + smC[3][row];
            float tnew = (S - 1.f) / C;
            if (C > 0.f && tnew > tau[r]) { tau[r] = tnew; done = 0; }
        }
        if (__syncthreads_and(done)) break;
    }

    // ---- probs -> slot lists (support ~4; cap 16, overflow prob ~1e-9) ----
    if (tid < 16) cnt16[tid] = 0;
    __syncthreads();
#pragma unroll
    for (int t = 0; t < 16; t++)
#pragma unroll
        for (int r = 0; r < 4; r++) {
            float p = Cfr[t][r] - tau[r];
            if (p > 0.f) {
                int row = qd * 4 + r;
                int key = w * 256 + t * 16 + m16;
                int sl = atomicAdd(&cnt16[row], 1);
                if (sl < 16) { slotI[row][sl] = key; slotV[row][sl] = p; }
            }
        }
    __syncthreads();

    // ---- PV: lane (row, c) accumulates dims c*4..c*4+3 over <=16 slots ----
    int prow = tid >> 4, pc = tid & 15;
    int n = min(cnt16[prow], 16);
    float4 accо = make_float4(0.f, 0.f, 0.f, 0.f);
    for (int sl = 0; sl < n; sl++) {
        int key = slotI[prow][sl];
        float p = slotV[prow][sl];
        float4 vv = *(const float4*)(vsh + (size_t)(kbase + key) * DH + pc * 4);
        accо.x += p * vv.x;
        accо.y += p * vv.y;
        accо.z += p * vv.z;
        accо.w += p * vv.w;
    }
    {
        unsigned short b0 = f2bf(accо.x), b1 = f2bf(accо.y), b2 = f2bf(accо.z), b3 = f2bf(accо.w);
        *(uint2*)(och + (size_t)(row0g + prow) * D_ + h * DH + pc * 4) =
            make_uint2((unsigned)b0 | ((unsigned)b1 << 16), (unsigned)b2 | ((unsigned)b3 << 16));
    }

    // ---- export slot lists for avg_reduce ----
    {
        int row = tid >> 4, sl = tid & 15;
        int nn = min(cnt16[row], 16);
        size_t base = ((size_t)(row0g + row) * H_ + h) * 16;
        if (sl == 0) scnt[(row0g + row) * H_ + h] = nn;
        if (sl < nn) {
            sidx[base + sl] = (unsigned short)slotI[row][sl];
            sval[base + sl] = f2bf(slotV[row][sl]);
        }
    }
}

// ---------------- avg_attention: per-row reduction over 16 heads ----------------
__global__ __launch_bounds__(256) void avg_reduce(const unsigned short* __restrict__ sidx,
                                                  const unsigned short* __restrict__ sval,
                                                  const int* __restrict__ scnt,
                                                  float* __restrict__ avg) {
    __shared__ float accv[1024];
    int tid = threadIdx.x;
    int grow = blockIdx.x;
    for (int i = tid; i < 1024; i += 256) accv[i] = 0.f;
    __syncthreads();
    int h = tid >> 4, sl = tid & 15;
    int n = scnt[grow * H_ + h];
    if (sl < n) {
        size_t base = ((size_t)grow * H_ + h) * 16;
        int idx = sidx[base + sl];
        float v = bf2f(sval[base + sl]);
        atomicAdd(&accv[idx], v);
    }
    __syncthreads();
    float* dst = avg + (size_t)grow * S_;
    for (int i = tid; i < 256; i += 256) {
        float4 o;
        o.x = accv[i * 4 + 0] * 0.0625f;
        o.y = accv[i * 4 + 1] * 0.0625f;
        o.z = accv[i * 4 + 2] * 0.0625f;
        o.w = accv[i * 4 + 3] * 0.0625f;
        *(float4*)(dst + i * 4) = o;
    }
}

extern "C" void kernel_launch(void* const* d_in, const int* in_sizes, int n_in,
                              void* d_out, int out_size, void* d_ws, size_t ws_size,
                              hipStream_t stream) {
    const float* x  = (const float*)d_in[0];
    const float* Wq = (const float*)d_in[1];
    const float* bq = (const float*)d_in[2];
    const float* Wk = (const float*)d_in[3];
    const float* bk = (const float*)d_in[4];
    const float* Wv = (const float*)d_in[5];
    const float* bv = (const float*)d_in[6];
    const float* Wo = (const float*)d_in[7];
    const float* bo = (const float*)d_in[8];

    float* xout = (float*)d_out;                   // (B,S,D)
    float* avg  = xout + (size_t)BS * D_;          // (B,S,S)

    char* ws = (char*)d_ws;
    unsigned short* qhB  = (unsigned short*)(ws + 0);               // 8 MB
    unsigned short* qlB  = (unsigned short*)(ws + (8u << 20));      // 8 MB
    unsigned short* khB  = (unsigned short*)(ws + (16u << 20));     // 8 MB
    unsigned short* klB  = (unsigned short*)(ws + (24u << 20));     // 8 MB
    unsigned short* WTh  = (unsigned short*)(ws + (32u << 20));     // 2 MB (alias: sidx)
    unsigned short* WTl  = (unsigned short*)(ws + (34u << 20));     // 2 MB (alias: sval)
    unsigned short* WoTh = (unsigned short*)(ws + (36u << 20));     // 2 MB
    unsigned short* ochB = (unsigned short*)(ws + (38u << 20));     // 8 MB
    float* vshb = (float*)(ws + (46u << 20));                       // 1 MB
    float* Wvsh = (float*)(ws + (47u << 20));                       // 256 KB (alias: scnt)
    float* bvsh = (float*)(ws + (47u << 20) + (320u << 10));        // tiny
    unsigned short* sidx = WTh;
    unsigned short* sval = WTl;
    int* scnt = (int*)Wvsh;

    dim3 ggrid(D_ / 64, BS / 128);

    wTsplit<<<1024, 256, 0, stream>>>(Wo, WoTh, nullptr, 0);
    wv_reduce_kernel<<<256, 256, 0, stream>>>(Wv, bv, Wvsh, bvsh);
    sgemm64<<<dim3(1, BS / 64), 256, 0, stream>>>(x, Wvsh, bvsh, vshb, BS, DH, D_);

    wTsplit<<<1024, 256, 0, stream>>>(Wq, WTh, WTl, 1);
    bgemm<1, 1><<<ggrid, 256, 0, stream>>>(x, nullptr, WTh, WTl, bq, nullptr, qhB, qlB);
    wTsplit<<<1024, 256, 0, stream>>>(Wk, WTh, WTl, 1);
    bgemm<1, 1><<<ggrid, 256, 0, stream>>>(x, nullptr, WTh, WTl, bk, nullptr, khB, klB);

    attn4<<<4096, 256, 0, stream>>>(qhB, qlB, khB, klB, vshb, ochB, sidx, sval, scnt);
    avg_reduce<<<4096, 256, 0, stream>>>(sidx, sval, scnt, avg);

    bgemm<0, 0><<<ggrid, 256, 0, stream>>>(nullptr, ochB, WoTh, nullptr, bo, xout, nullptr, nullptr);
}

// Round 5
// 714.012 us; speedup vs baseline: 2.6989x; 1.0124x over previous
//
#include <hip/hip_runtime.h>

#define B_  4
#define S_  1024
#define D_  1024
#define H_  16
#define DH  64
#define BS  4096   // B_*S_

typedef __bf16 bf16x8 __attribute__((ext_vector_type(8)));
typedef float  f32x4  __attribute__((ext_vector_type(4)));

__device__ __forceinline__ unsigned short f2bf(float f) {
    __bf16 b = (__bf16)f;
    return __builtin_bit_cast(unsigned short, b);
}
__device__ __forceinline__ float bf2f(unsigned short u) {
    return (float)__builtin_bit_cast(__bf16, u);
}

// ---------------- Wv head-mean reduction (fp32) ----------------
__global__ void wv_reduce_kernel(const float* __restrict__ Wv, const float* __restrict__ bv,
                                 float* __restrict__ Wvsh, float* __restrict__ bvsh) {
    int e = blockIdx.x * 256 + threadIdx.x;
    if (e < D_ * DH) {
        int d = e >> 6, j = e & 63;
        float s = 0.f;
#pragma unroll
        for (int h = 0; h < H_; h++) s += Wv[d * D_ + h * DH + j];
        Wvsh[e] = s * (1.f / 16.f);
    }
    if (e < DH) {
        float s = 0.f;
#pragma unroll
        for (int h = 0; h < H_; h++) s += bv[h * DH + e];
        bvsh[e] = s * (1.f / 16.f);
    }
}

// ---------------- 64x64 fp32 SGEMM + bias (v_shared, N=64) ----------------
__global__ __launch_bounds__(256) void sgemm64(const float* __restrict__ A,
                                               const float* __restrict__ Bm,
                                               const float* __restrict__ bias,
                                               float* __restrict__ C,
                                               int M, int N, int K) {
    __shared__ float As[16][68];
    __shared__ float Bs[16][68];
    int tid = threadIdx.x;
    int bm = blockIdx.y, bn = blockIdx.x;
    int tx = tid & 15, ty = tid >> 4;
    int la_m = tid >> 2, la_k4 = (tid & 3) * 4;
    int lb_k = tid >> 4, lb_n4 = (tid & 15) * 4;

    float acc[4][4];
#pragma unroll
    for (int i = 0; i < 4; i++)
#pragma unroll
        for (int j = 0; j < 4; j++) acc[i][j] = 0.f;

    for (int k0 = 0; k0 < K; k0 += 16) {
        float4 a4 = *(const float4*)(A + (size_t)(bm * 64 + la_m) * K + k0 + la_k4);
        float4 b4 = *(const float4*)(Bm + (size_t)(k0 + lb_k) * N + bn * 64 + lb_n4);
        __syncthreads();
        As[la_k4 + 0][la_m] = a4.x;
        As[la_k4 + 1][la_m] = a4.y;
        As[la_k4 + 2][la_m] = a4.z;
        As[la_k4 + 3][la_m] = a4.w;
        *(float4*)&Bs[lb_k][lb_n4] = b4;
        __syncthreads();
#pragma unroll
        for (int kk = 0; kk < 16; kk++) {
            float4 a0 = *(float4*)&As[kk][ty * 4];
            float4 b0 = *(float4*)&Bs[kk][tx * 4];
            float av[4] = {a0.x, a0.y, a0.z, a0.w};
            float bw[4] = {b0.x, b0.y, b0.z, b0.w};
#pragma unroll
            for (int i = 0; i < 4; i++)
#pragma unroll
                for (int j = 0; j < 4; j++) acc[i][j] += av[i] * bw[j];
        }
    }
#pragma unroll
    for (int r = 0; r < 4; r++) {
        int row = bm * 64 + ty * 4 + r;
        int col = bn * 64 + tx * 4;
        float4 bb = *(const float4*)(bias + col);
        float4 o;
        o.x = acc[r][0] + bb.x;
        o.y = acc[r][1] + bb.y;
        o.z = acc[r][2] + bb.z;
        o.w = acc[r][3] + bb.w;
        *(float4*)(C + (size_t)row * N + col) = o;
    }
}

// ---------------- transpose + bf16 hi/lo split of a DxD weight ----------------
__global__ __launch_bounds__(256) void wTsplit(const float* __restrict__ W,
                                               unsigned short* __restrict__ Th,
                                               unsigned short* __restrict__ Tl,
                                               int wantLo) {
    __shared__ float tile[32][33];
    int tid = threadIdx.x;
    int tn = blockIdx.x & 31, tk = blockIdx.x >> 5;
    int r = tid >> 3, c4 = (tid & 7) * 4;
    float4 v = *(const float4*)(W + (size_t)(tk * 32 + r) * D_ + tn * 32 + c4);
    tile[r][c4 + 0] = v.x;
    tile[r][c4 + 1] = v.y;
    tile[r][c4 + 2] = v.z;
    tile[r][c4 + 3] = v.w;
    __syncthreads();
    unsigned short hh[4], ll[4];
#pragma unroll
    for (int i = 0; i < 4; i++) {
        float f = tile[c4 + i][r];
        hh[i] = f2bf(f);
        ll[i] = f2bf(f - bf2f(hh[i]));
    }
    size_t off = (size_t)(tn * 32 + r) * D_ + tk * 32 + c4;
    *(uint2*)(Th + off) = make_uint2((unsigned)hh[0] | ((unsigned)hh[1] << 16),
                                     (unsigned)hh[2] | ((unsigned)hh[3] << 16));
    if (wantLo)
        *(uint2*)(Tl + off) = make_uint2((unsigned)ll[0] | ((unsigned)ll[1] << 16),
                                         (unsigned)ll[2] | ((unsigned)ll[3] << 16));
}

// ---------------- bf16 MFMA GEMM, 128x64 tile, B^T layout ----------------
template<int HILO, int OUTMODE>
__global__ __launch_bounds__(256) void bgemm(const float* __restrict__ Afp,
                                             const unsigned short* __restrict__ Abf,
                                             const unsigned short* __restrict__ Bh,
                                             const unsigned short* __restrict__ Bl,
                                             const float* __restrict__ bias,
                                             float* __restrict__ Cf,
                                             unsigned short* __restrict__ Ch,
                                             unsigned short* __restrict__ Cl) {
    __shared__ unsigned short AhS[128 * 32];
    __shared__ unsigned short AlS[HILO ? 128 * 32 : 8];
    __shared__ unsigned short BhS[64 * 32];
    __shared__ unsigned short BlS[HILO ? 64 * 32 : 8];

    int tid = threadIdx.x;
    int bn = blockIdx.x, bm = blockIdx.y;
    int w = tid >> 6, lane = tid & 63;
    int m16 = lane & 15, qd = lane >> 4;
    int rh = (w >> 1) * 64, ch = (w & 1) * 32;

    f32x4 acc[4][2];
#pragma unroll
    for (int it = 0; it < 4; it++)
#pragma unroll
        for (int jt = 0; jt < 2; jt++) acc[it][jt] = (f32x4){0.f, 0.f, 0.f, 0.f};

    for (int k0 = 0; k0 < D_; k0 += 32) {
        __syncthreads();
        if (HILO) {
#pragma unroll
            for (int i = 0; i < 2; i++) {
                int idx = i * 256 + tid;
                int row = idx >> 2, seg = idx & 3;
                const float* src = Afp + (size_t)(bm * 128 + row) * D_ + k0 + seg * 8;
                float4 v0 = *(const float4*)src;
                float4 v1 = *(const float4*)(src + 4);
                float vv[8] = {v0.x, v0.y, v0.z, v0.w, v1.x, v1.y, v1.z, v1.w};
                unsigned int hw[4], lw[4];
#pragma unroll
                for (int j = 0; j < 4; j++) {
                    unsigned short h0 = f2bf(vv[2 * j]), h1 = f2bf(vv[2 * j + 1]);
                    unsigned short l0 = f2bf(vv[2 * j] - bf2f(h0));
                    unsigned short l1 = f2bf(vv[2 * j + 1] - bf2f(h1));
                    hw[j] = (unsigned)h0 | ((unsigned)h1 << 16);
                    lw[j] = (unsigned)l0 | ((unsigned)l1 << 16);
                }
                *(uint4*)((char*)AhS + idx * 16) = make_uint4(hw[0], hw[1], hw[2], hw[3]);
                *(uint4*)((char*)AlS + idx * 16) = make_uint4(lw[0], lw[1], lw[2], lw[3]);
            }
        } else {
#pragma unroll
            for (int i = 0; i < 2; i++) {
                int idx = i * 256 + tid;
                int row = idx >> 2, seg = idx & 3;
                uint4 v = *(const uint4*)(Abf + (size_t)(bm * 128 + row) * D_ + k0 + seg * 8);
                *(uint4*)((char*)AhS + idx * 16) = v;
            }
        }
        {
            int row = tid >> 2, seg = tid & 3;
            uint4 v = *(const uint4*)(Bh + (size_t)(bn * 64 + row) * D_ + k0 + seg * 8);
            *(uint4*)((char*)BhS + tid * 16) = v;
            if (HILO) {
                uint4 v2 = *(const uint4*)(Bl + (size_t)(bn * 64 + row) * D_ + k0 + seg * 8);
                *(uint4*)((char*)BlS + tid * 16) = v2;
            }
        }
        __syncthreads();
        bf16x8 ah[4], al[4], bh2[2], bl2[2];
#pragma unroll
        for (int it = 0; it < 4; it++) {
            ah[it] = *(const bf16x8*)((char*)AhS + (rh + it * 16 + m16) * 64 + qd * 16);
            if (HILO) al[it] = *(const bf16x8*)((char*)AlS + (rh + it * 16 + m16) * 64 + qd * 16);
        }
#pragma unroll
        for (int jt = 0; jt < 2; jt++) {
            bh2[jt] = *(const bf16x8*)((char*)BhS + (ch + jt * 16 + m16) * 64 + qd * 16);
            if (HILO) bl2[jt] = *(const bf16x8*)((char*)BlS + (ch + jt * 16 + m16) * 64 + qd * 16);
        }
#pragma unroll
        for (int it = 0; it < 4; it++)
#pragma unroll
            for (int jt = 0; jt < 2; jt++) {
                acc[it][jt] = __builtin_amdgcn_mfma_f32_16x16x32_bf16(ah[it], bh2[jt], acc[it][jt], 0, 0, 0);
                if (HILO) {
                    acc[it][jt] = __builtin_amdgcn_mfma_f32_16x16x32_bf16(ah[it], bl2[jt], acc[it][jt], 0, 0, 0);
                    acc[it][jt] = __builtin_amdgcn_mfma_f32_16x16x32_bf16(al[it], bh2[jt], acc[it][jt], 0, 0, 0);
                }
            }
    }
#pragma unroll
    for (int it = 0; it < 4; it++)
#pragma unroll
        for (int jt = 0; jt < 2; jt++)
#pragma unroll
            for (int r = 0; r < 4; r++) {
                int R = bm * 128 + rh + it * 16 + qd * 4 + r;
                int Cc = bn * 64 + ch + jt * 16 + m16;
                float v = acc[it][jt][r] + bias[Cc];
                if (OUTMODE == 0) {
                    Cf[(size_t)R * D_ + Cc] = v;
                } else {
                    unsigned short h0 = f2bf(v);
                    Ch[(size_t)R * D_ + Cc] = h0;
                    Cl[(size_t)R * D_ + Cc] = f2bf(v - bf2f(h0));
                }
            }
}

// ---------------- fused attention v6 ----------------
// grid 4096, XCD-swizzled. MFMA hi/lo logits in regs -> candidate compaction
// (fast path for tau) with FULL-REGISTER Newton fallback on cap overflow ->
// slot extraction ALWAYS from registers (correct regardless of cap).
#define CCAP 48
__global__ __launch_bounds__(256, 2) void attn6(const unsigned short* __restrict__ qh,
                                                const unsigned short* __restrict__ ql,
                                                const unsigned short* __restrict__ kh,
                                                const unsigned short* __restrict__ kl,
                                                const float* __restrict__ vsh,
                                                unsigned short* __restrict__ och,
                                                unsigned short* __restrict__ sidx,
                                                unsigned short* __restrict__ sval,
                                                int* __restrict__ scnt) {
    __shared__ float smM[4][16];
    __shared__ float smS[4][16], smC[4][16];
    __shared__ float tau0s[16];
    __shared__ float taus[16];
    __shared__ float candV[16][CCAP];
    __shared__ int   ccnt[16];
    __shared__ int   ovfAny;
    __shared__ int   scnt16[16];
    __shared__ short slotI[16][16];
    __shared__ float slotV[16][16];

    int tid = threadIdx.x, w = tid >> 6, lane = tid & 63;
    int m16 = lane & 15, qd = lane >> 4;

    // XCD-aware swizzle: xcd = bid&7 owns bh slices {xcd, 8+xcd, ...}
    int bid = blockIdx.x;
    int xcd = bid & 7;
    int j   = bid >> 3;
    int bh  = ((j & 7) << 3) | xcd;   // 0..63
    int qt  = j >> 3;                 // 0..63
    int bb  = bh >> 4, h = bh & 15;
    int row0g = bb * S_ + qt * 16;
    int kbase = bb * S_;

    // Q A-frags (rows row0g+m16), k-chunks 0/1, hi+lo
    bf16x8 aH[2], aL[2];
#pragma unroll
    for (int c = 0; c < 2; c++) {
        size_t off = (size_t)(row0g + m16) * D_ + h * DH + c * 32 + qd * 8;
        aH[c] = *(const bf16x8*)(qh + off);
        aL[c] = *(const bf16x8*)(ql + off);
    }

    f32x4 Cfr[16];
#pragma unroll
    for (int t = 0; t < 16; t++) Cfr[t] = (f32x4){0.f, 0.f, 0.f, 0.f};

#pragma unroll 4
    for (int t = 0; t < 16; t++) {
        int n0 = w * 256 + t * 16;
        bf16x8 bH[2], bL[2];
#pragma unroll
        for (int c = 0; c < 2; c++) {
            size_t boff = (size_t)(kbase + n0 + m16) * D_ + h * DH + c * 32 + qd * 8;
            bH[c] = *(const bf16x8*)(kh + boff);
            bL[c] = *(const bf16x8*)(kl + boff);
        }
        f32x4 a = Cfr[t];
        a = __builtin_amdgcn_mfma_f32_16x16x32_bf16(aH[0], bH[0], a, 0, 0, 0);
        a = __builtin_amdgcn_mfma_f32_16x16x32_bf16(aH[1], bH[1], a, 0, 0, 0);
        a = __builtin_amdgcn_mfma_f32_16x16x32_bf16(aH[0], bL[0], a, 0, 0, 0);
        a = __builtin_amdgcn_mfma_f32_16x16x32_bf16(aH[1], bL[1], a, 0, 0, 0);
        a = __builtin_amdgcn_mfma_f32_16x16x32_bf16(aL[0], bH[0], a, 0, 0, 0);
        a = __builtin_amdgcn_mfma_f32_16x16x32_bf16(aL[1], bH[1], a, 0, 0, 0);
        Cfr[t] = a;
    }
#pragma unroll
    for (int t = 0; t < 16; t++)
#pragma unroll
        for (int r = 0; r < 4; r++) Cfr[t][r] *= 0.125f;

    // ---- row max -> tau0 ----
    float mxr[4];
#pragma unroll
    for (int r = 0; r < 4; r++) mxr[r] = -3.0e38f;
#pragma unroll
    for (int t = 0; t < 16; t++)
#pragma unroll
        for (int r = 0; r < 4; r++) mxr[r] = fmaxf(mxr[r], Cfr[t][r]);
#pragma unroll
    for (int off = 8; off >= 1; off >>= 1)
#pragma unroll
        for (int r = 0; r < 4; r++) mxr[r] = fmaxf(mxr[r], __shfl_xor(mxr[r], off, 16));
    if (m16 == 0)
#pragma unroll
        for (int r = 0; r < 4; r++) smM[w][qd * 4 + r] = mxr[r];
    if (tid < 16) ccnt[tid] = 0;
    if (tid == 0) ovfAny = 0;
    __syncthreads();
    if (tid < 16)
        tau0s[tid] = fmaxf(fmaxf(smM[0][tid], smM[1][tid]), fmaxf(smM[2][tid], smM[3][tid])) - 1.0f;
    __syncthreads();

    // ---- candidate compaction (values only; used solely to find tau) ----
#pragma unroll
    for (int t = 0; t < 16; t++)
#pragma unroll
        for (int r = 0; r < 4; r++) {
            float z = Cfr[t][r];
            int row = qd * 4 + r;
            if (z > tau0s[row]) {
                int pos = atomicAdd(&ccnt[row], 1);
                if (pos < CCAP) candV[row][pos] = z;
            }
        }
    __syncthreads();
    if (tid < 16 && ccnt[tid] > CCAP) ovfAny = 1;

    // ---- fast-path Newton over candidates: 16 threads per row ----
    int prow = tid >> 4, pc = tid & 15;
    {
        int nc = ccnt[prow];
        float tau = tau0s[prow];
        if (nc <= CCAP) {
            float z0 = (pc < nc)      ? candV[prow][pc]      : -3.0e38f;
            float z1 = (pc + 16 < nc) ? candV[prow][pc + 16] : -3.0e38f;
            float z2 = (pc + 32 < nc) ? candV[prow][pc + 32] : -3.0e38f;
            for (int it = 0; it < CCAP; it++) {
                float s = 0.f, c = 0.f;
                if (z0 > tau) { s += z0; c += 1.f; }
                if (z1 > tau) { s += z1; c += 1.f; }
                if (z2 > tau) { s += z2; c += 1.f; }
#pragma unroll
                for (int off = 8; off >= 1; off >>= 1) {
                    s += __shfl_xor(s, off, 16);
                    c += __shfl_xor(c, off, 16);
                }
                float tnew = (s - 1.f) / c;
                if (tnew > tau) tau = tnew; else break;
            }
        }
        if (pc == 0) taus[prow] = tau;   // overflow rows keep tau0
    }
    __syncthreads();

    // ---- rare fallback: full-register block Newton (rows at fixed point don't move) ----
    if (ovfAny) {
        for (int it = 0; it < 64; it++) {
            float s[4], c[4];
#pragma unroll
            for (int r = 0; r < 4; r++) { s[r] = 0.f; c[r] = 0.f; }
#pragma unroll
            for (int t = 0; t < 16; t++)
#pragma unroll
                for (int r = 0; r < 4; r++) {
                    float z = Cfr[t][r];
                    if (z > taus[qd * 4 + r]) { s[r] += z; c[r] += 1.f; }
                }
#pragma unroll
            for (int off = 8; off >= 1; off >>= 1)
#pragma unroll
                for (int r = 0; r < 4; r++) {
                    s[r] += __shfl_xor(s[r], off, 16);
                    c[r] += __shfl_xor(c[r], off, 16);
                }
            if (m16 == 0)
#pragma unroll
                for (int r = 0; r < 4; r++) {
                    smS[w][qd * 4 + r] = s[r];
                    smC[w][qd * 4 + r] = c[r];
                }
            __syncthreads();
            int done = 1;
            if (tid < 16) {
                float S = smS[0][tid] + smS[1][tid] + smS[2][tid] + smS[3][tid];
                float C = smC[0][tid] + smC[1][tid] + smC[2][tid] + smC[3][tid];
                float tnew = (S - 1.f) / C;
                if (C > 0.f && tnew > taus[tid]) { taus[tid] = tnew; done = 0; }
            }
            if (__syncthreads_and(done)) break;
        }
    }

    // ---- slot extraction from REGISTERS (correct for all rows) ----
    if (tid < 16) scnt16[tid] = 0;
    __syncthreads();
#pragma unroll
    for (int t = 0; t < 16; t++)
#pragma unroll
        for (int r = 0; r < 4; r++) {
            int row = qd * 4 + r;
            float p = Cfr[t][r] - taus[row];
            if (p > 0.f) {
                int sl = atomicAdd(&scnt16[row], 1);
                if (sl < 16) {
                    slotI[row][sl] = (short)(w * 256 + t * 16 + m16);
                    slotV[row][sl] = p;
                }
            }
        }
    __syncthreads();

    // ---- PV: lane (prow, pc) accumulates dims pc*4..pc*4+3 ----
    int nsl = min(scnt16[prow], 16);
    float4 accq = make_float4(0.f, 0.f, 0.f, 0.f);
    for (int sl = 0; sl < nsl; sl++) {
        int key = slotI[prow][sl];
        float p = slotV[prow][sl];
        float4 vv = *(const float4*)(vsh + (size_t)(kbase + key) * DH + pc * 4);
        accq.x += p * vv.x;
        accq.y += p * vv.y;
        accq.z += p * vv.z;
        accq.w += p * vv.w;
    }
    {
        unsigned short b0 = f2bf(accq.x), b1 = f2bf(accq.y), b2 = f2bf(accq.z), b3 = f2bf(accq.w);
        *(uint2*)(och + (size_t)(row0g + prow) * D_ + h * DH + pc * 4) =
            make_uint2((unsigned)b0 | ((unsigned)b1 << 16), (unsigned)b2 | ((unsigned)b3 << 16));
    }

    // ---- export slot lists for avg_reduce ----
    {
        size_t base = ((size_t)(row0g + prow) * H_ + h) * 16;
        if (pc == 0) scnt[(row0g + prow) * H_ + h] = nsl;
        if (pc < nsl) {
            sidx[base + pc] = (unsigned short)slotI[prow][pc];
            sval[base + pc] = f2bf(slotV[prow][pc]);
        }
    }
}

// ---------------- avg_attention: per-row reduction over 16 heads ----------------
__global__ __launch_bounds__(256) void avg_reduce(const unsigned short* __restrict__ sidx,
                                                  const unsigned short* __restrict__ sval,
                                                  const int* __restrict__ scnt,
                                                  float* __restrict__ avg) {
    __shared__ float accv[1024];
    int tid = threadIdx.x;
    int grow = blockIdx.x;
    for (int i = tid; i < 1024; i += 256) accv[i] = 0.f;
    __syncthreads();
    int h = tid >> 4, sl = tid & 15;
    int n = scnt[grow * H_ + h];
    if (sl < n) {
        size_t base = ((size_t)grow * H_ + h) * 16;
        int idx = sidx[base + sl];
        float v = bf2f(sval[base + sl]);
        atomicAdd(&accv[idx], v);
    }
    __syncthreads();
    float* dst = avg + (size_t)grow * S_;
    for (int i = tid; i < 256; i += 256) {
        float4 o;
        o.x = accv[i * 4 + 0] * 0.0625f;
        o.y = accv[i * 4 + 1] * 0.0625f;
        o.z = accv[i * 4 + 2] * 0.0625f;
        o.w = accv[i * 4 + 3] * 0.0625f;
        *(float4*)(dst + i * 4) = o;
    }
}

extern "C" void kernel_launch(void* const* d_in, const int* in_sizes, int n_in,
                              void* d_out, int out_size, void* d_ws, size_t ws_size,
                              hipStream_t stream) {
    const float* x  = (const float*)d_in[0];
    const float* Wq = (const float*)d_in[1];
    const float* bq = (const float*)d_in[2];
    const float* Wk = (const float*)d_in[3];
    const float* bk = (const float*)d_in[4];
    const float* Wv = (const float*)d_in[5];
    const float* bv = (const float*)d_in[6];
    const float* Wo = (const float*)d_in[7];
    const float* bo = (const float*)d_in[8];

    float* xout = (float*)d_out;                   // (B,S,D)
    float* avg  = xout + (size_t)BS * D_;          // (B,S,S)

    char* ws = (char*)d_ws;
    unsigned short* qhB  = (unsigned short*)(ws + 0);               // 8 MB
    unsigned short* qlB  = (unsigned short*)(ws + (8u << 20));      // 8 MB
    unsigned short* khB  = (unsigned short*)(ws + (16u << 20));     // 8 MB
    unsigned short* klB  = (unsigned short*)(ws + (24u << 20));     // 8 MB
    unsigned short* WTh  = (unsigned short*)(ws + (32u << 20));     // 2 MB (alias: sidx)
    unsigned short* WTl  = (unsigned short*)(ws + (34u << 20));     // 2 MB (alias: sval)
    unsigned short* WoTh = (unsigned short*)(ws + (36u << 20));     // 2 MB
    unsigned short* ochB = (unsigned short*)(ws + (38u << 20));     // 8 MB
    float* vshb = (float*)(ws + (46u << 20));                       // 1 MB
    float* Wvsh = (float*)(ws + (47u << 20));                       // 256 KB (alias: scnt)
    float* bvsh = (float*)(ws + (47u << 20) + (320u << 10));        // tiny
    unsigned short* sidx = WTh;
    unsigned short* sval = WTl;
    int* scnt = (int*)Wvsh;

    dim3 ggrid(D_ / 64, BS / 128);

    wTsplit<<<1024, 256, 0, stream>>>(Wo, WoTh, nullptr, 0);
    wv_reduce_kernel<<<256, 256, 0, stream>>>(Wv, bv, Wvsh, bvsh);
    sgemm64<<<dim3(1, BS / 64), 256, 0, stream>>>(x, Wvsh, bvsh, vshb, BS, DH, D_);

    wTsplit<<<1024, 256, 0, stream>>>(Wq, WTh, WTl, 1);
    bgemm<1, 1><<<ggrid, 256, 0, stream>>>(x, nullptr, WTh, WTl, bq, nullptr, qhB, qlB);
    wTsplit<<<1024, 256, 0, stream>>>(Wk, WTh, WTl, 1);
    bgemm<1, 1><<<ggrid, 256, 0, stream>>>(x, nullptr, WTh, WTl, bk, nullptr, khB, klB);

    attn6<<<4096, 256, 0, stream>>>(qhB, qlB, khB, klB, vshb, ochB, sidx, sval, scnt);
    avg_reduce<<<4096, 256, 0, stream>>>(sidx, sval, scnt, avg);

    bgemm<0, 0><<<ggrid, 256, 0, stream>>>(nullptr, ochB, WoTh, nullptr, bo, xout, nullptr, nullptr);
}

// Round 6
// 448.597 us; speedup vs baseline: 4.2958x; 1.5917x over previous
//
#include <hip/hip_runtime.h>

#define B_  4
#define S_  1024
#define D_  1024
#define H_  16
#define DH  64
#define BS  4096   // B_*S_

typedef __bf16 bf16x8 __attribute__((ext_vector_type(8)));
typedef float  f32x4  __attribute__((ext_vector_type(4)));

__device__ __forceinline__ unsigned short f2bf(float f) {
    __bf16 b = (__bf16)f;
    return __builtin_bit_cast(unsigned short, b);
}
__device__ __forceinline__ float bf2f(unsigned short u) {
    return (float)__builtin_bit_cast(__bf16, u);
}

// ---------------- Wv head-mean reduction (fp32) ----------------
__global__ void wv_reduce_kernel(const float* __restrict__ Wv, const float* __restrict__ bv,
                                 float* __restrict__ Wvsh, float* __restrict__ bvsh) {
    int e = blockIdx.x * 256 + threadIdx.x;
    if (e < D_ * DH) {
        int d = e >> 6, j = e & 63;
        float s = 0.f;
#pragma unroll
        for (int h = 0; h < H_; h++) s += Wv[d * D_ + h * DH + j];
        Wvsh[e] = s * (1.f / 16.f);
    }
    if (e < DH) {
        float s = 0.f;
#pragma unroll
        for (int h = 0; h < H_; h++) s += bv[h * DH + e];
        bvsh[e] = s * (1.f / 16.f);
    }
}

// ---------------- 64x64 fp32 SGEMM + bias (v_shared, N=64) ----------------
__global__ __launch_bounds__(256) void sgemm64(const float* __restrict__ A,
                                               const float* __restrict__ Bm,
                                               const float* __restrict__ bias,
                                               float* __restrict__ C,
                                               int M, int N, int K) {
    __shared__ float As[16][68];
    __shared__ float Bs[16][68];
    int tid = threadIdx.x;
    int bm = blockIdx.y, bn = blockIdx.x;
    int tx = tid & 15, ty = tid >> 4;
    int la_m = tid >> 2, la_k4 = (tid & 3) * 4;
    int lb_k = tid >> 4, lb_n4 = (tid & 15) * 4;

    float acc[4][4];
#pragma unroll
    for (int i = 0; i < 4; i++)
#pragma unroll
        for (int j = 0; j < 4; j++) acc[i][j] = 0.f;

    for (int k0 = 0; k0 < K; k0 += 16) {
        float4 a4 = *(const float4*)(A + (size_t)(bm * 64 + la_m) * K + k0 + la_k4);
        float4 b4 = *(const float4*)(Bm + (size_t)(k0 + lb_k) * N + bn * 64 + lb_n4);
        __syncthreads();
        As[la_k4 + 0][la_m] = a4.x;
        As[la_k4 + 1][la_m] = a4.y;
        As[la_k4 + 2][la_m] = a4.z;
        As[la_k4 + 3][la_m] = a4.w;
        *(float4*)&Bs[lb_k][lb_n4] = b4;
        __syncthreads();
#pragma unroll
        for (int kk = 0; kk < 16; kk++) {
            float4 a0 = *(float4*)&As[kk][ty * 4];
            float4 b0 = *(float4*)&Bs[kk][tx * 4];
            float av[4] = {a0.x, a0.y, a0.z, a0.w};
            float bw[4] = {b0.x, b0.y, b0.z, b0.w};
#pragma unroll
            for (int i = 0; i < 4; i++)
#pragma unroll
                for (int j = 0; j < 4; j++) acc[i][j] += av[i] * bw[j];
        }
    }
#pragma unroll
    for (int r = 0; r < 4; r++) {
        int row = bm * 64 + ty * 4 + r;
        int col = bn * 64 + tx * 4;
        float4 bb = *(const float4*)(bias + col);
        float4 o;
        o.x = acc[r][0] + bb.x;
        o.y = acc[r][1] + bb.y;
        o.z = acc[r][2] + bb.z;
        o.w = acc[r][3] + bb.w;
        *(float4*)(C + (size_t)row * N + col) = o;
    }
}

// ---------------- transpose + bf16 hi/lo split of a DxD weight ----------------
__global__ __launch_bounds__(256) void wTsplit(const float* __restrict__ W,
                                               unsigned short* __restrict__ Th,
                                               unsigned short* __restrict__ Tl,
                                               int wantLo) {
    __shared__ float tile[32][33];
    int tid = threadIdx.x;
    int tn = blockIdx.x & 31, tk = blockIdx.x >> 5;
    int r = tid >> 3, c4 = (tid & 7) * 4;
    float4 v = *(const float4*)(W + (size_t)(tk * 32 + r) * D_ + tn * 32 + c4);
    tile[r][c4 + 0] = v.x;
    tile[r][c4 + 1] = v.y;
    tile[r][c4 + 2] = v.z;
    tile[r][c4 + 3] = v.w;
    __syncthreads();
    unsigned short hh[4], ll[4];
#pragma unroll
    for (int i = 0; i < 4; i++) {
        float f = tile[c4 + i][r];
        hh[i] = f2bf(f);
        ll[i] = f2bf(f - bf2f(hh[i]));
    }
    size_t off = (size_t)(tn * 32 + r) * D_ + tk * 32 + c4;
    *(uint2*)(Th + off) = make_uint2((unsigned)hh[0] | ((unsigned)hh[1] << 16),
                                     (unsigned)hh[2] | ((unsigned)hh[3] << 16));
    if (wantLo)
        *(uint2*)(Tl + off) = make_uint2((unsigned)ll[0] | ((unsigned)ll[1] << 16),
                                         (unsigned)ll[2] | ((unsigned)ll[3] << 16));
}

// ---------------- bf16 MFMA GEMM, 128x64 tile, B^T layout ----------------
template<int HILO, int OUTMODE>
__global__ __launch_bounds__(256) void bgemm(const float* __restrict__ Afp,
                                             const unsigned short* __restrict__ Abf,
                                             const unsigned short* __restrict__ Bh,
                                             const unsigned short* __restrict__ Bl,
                                             const float* __restrict__ bias,
                                             float* __restrict__ Cf,
                                             unsigned short* __restrict__ Ch,
                                             unsigned short* __restrict__ Cl) {
    __shared__ unsigned short AhS[128 * 32];
    __shared__ unsigned short AlS[HILO ? 128 * 32 : 8];
    __shared__ unsigned short BhS[64 * 32];
    __shared__ unsigned short BlS[HILO ? 64 * 32 : 8];

    int tid = threadIdx.x;
    int bn = blockIdx.x, bm = blockIdx.y;
    int w = tid >> 6, lane = tid & 63;
    int m16 = lane & 15, qd = lane >> 4;
    int rh = (w >> 1) * 64, ch = (w & 1) * 32;

    f32x4 acc[4][2];
#pragma unroll
    for (int it = 0; it < 4; it++)
#pragma unroll
        for (int jt = 0; jt < 2; jt++) acc[it][jt] = (f32x4){0.f, 0.f, 0.f, 0.f};

    for (int k0 = 0; k0 < D_; k0 += 32) {
        __syncthreads();
        if (HILO) {
#pragma unroll
            for (int i = 0; i < 2; i++) {
                int idx = i * 256 + tid;
                int row = idx >> 2, seg = idx & 3;
                const float* src = Afp + (size_t)(bm * 128 + row) * D_ + k0 + seg * 8;
                float4 v0 = *(const float4*)src;
                float4 v1 = *(const float4*)(src + 4);
                float vv[8] = {v0.x, v0.y, v0.z, v0.w, v1.x, v1.y, v1.z, v1.w};
                unsigned int hw[4], lw[4];
#pragma unroll
                for (int j = 0; j < 4; j++) {
                    unsigned short h0 = f2bf(vv[2 * j]), h1 = f2bf(vv[2 * j + 1]);
                    unsigned short l0 = f2bf(vv[2 * j] - bf2f(h0));
                    unsigned short l1 = f2bf(vv[2 * j + 1] - bf2f(h1));
                    hw[j] = (unsigned)h0 | ((unsigned)h1 << 16);
                    lw[j] = (unsigned)l0 | ((unsigned)l1 << 16);
                }
                *(uint4*)((char*)AhS + idx * 16) = make_uint4(hw[0], hw[1], hw[2], hw[3]);
                *(uint4*)((char*)AlS + idx * 16) = make_uint4(lw[0], lw[1], lw[2], lw[3]);
            }
        } else {
#pragma unroll
            for (int i = 0; i < 2; i++) {
                int idx = i * 256 + tid;
                int row = idx >> 2, seg = idx & 3;
                uint4 v = *(const uint4*)(Abf + (size_t)(bm * 128 + row) * D_ + k0 + seg * 8);
                *(uint4*)((char*)AhS + idx * 16) = v;
            }
        }
        {
            int row = tid >> 2, seg = tid & 3;
            uint4 v = *(const uint4*)(Bh + (size_t)(bn * 64 + row) * D_ + k0 + seg * 8);
            *(uint4*)((char*)BhS + tid * 16) = v;
            if (HILO) {
                uint4 v2 = *(const uint4*)(Bl + (size_t)(bn * 64 + row) * D_ + k0 + seg * 8);
                *(uint4*)((char*)BlS + tid * 16) = v2;
            }
        }
        __syncthreads();
        bf16x8 ah[4], al[4], bh2[2], bl2[2];
#pragma unroll
        for (int it = 0; it < 4; it++) {
            ah[it] = *(const bf16x8*)((char*)AhS + (rh + it * 16 + m16) * 64 + qd * 16);
            if (HILO) al[it] = *(const bf16x8*)((char*)AlS + (rh + it * 16 + m16) * 64 + qd * 16);
        }
#pragma unroll
        for (int jt = 0; jt < 2; jt++) {
            bh2[jt] = *(const bf16x8*)((char*)BhS + (ch + jt * 16 + m16) * 64 + qd * 16);
            if (HILO) bl2[jt] = *(const bf16x8*)((char*)BlS + (ch + jt * 16 + m16) * 64 + qd * 16);
        }
#pragma unroll
        for (int it = 0; it < 4; it++)
#pragma unroll
            for (int jt = 0; jt < 2; jt++) {
                acc[it][jt] = __builtin_amdgcn_mfma_f32_16x16x32_bf16(ah[it], bh2[jt], acc[it][jt], 0, 0, 0);
                if (HILO) {
                    acc[it][jt] = __builtin_amdgcn_mfma_f32_16x16x32_bf16(ah[it], bl2[jt], acc[it][jt], 0, 0, 0);
                    acc[it][jt] = __builtin_amdgcn_mfma_f32_16x16x32_bf16(al[it], bh2[jt], acc[it][jt], 0, 0, 0);
                }
            }
    }
#pragma unroll
    for (int it = 0; it < 4; it++)
#pragma unroll
        for (int jt = 0; jt < 2; jt++)
#pragma unroll
            for (int r = 0; r < 4; r++) {
                int R = bm * 128 + rh + it * 16 + qd * 4 + r;
                int Cc = bn * 64 + ch + jt * 16 + m16;
                float v = acc[it][jt][r] + bias[Cc];
                if (OUTMODE == 0) {
                    Cf[(size_t)R * D_ + Cc] = v;
                } else {
                    unsigned short h0 = f2bf(v);
                    Ch[(size_t)R * D_ + Cc] = h0;
                    Cl[(size_t)R * D_ + Cc] = f2bf(v - bf2f(h0));
                }
            }
}

// ---------------- fused attention v7 ----------------
// Identical to v6 except the MFMA loop is FULLY unrolled: partial unroll made
// Cfr[] dynamically indexed -> scratch-spilled accumulators (1.8 GB of scratch
// traffic per dispatch, VGPR_Count 60). Full unroll keeps Cfr in VGPRs.
#define CCAP 48
__global__ __launch_bounds__(256, 2) void attn7(const unsigned short* __restrict__ qh,
                                                const unsigned short* __restrict__ ql,
                                                const unsigned short* __restrict__ kh,
                                                const unsigned short* __restrict__ kl,
                                                const float* __restrict__ vsh,
                                                unsigned short* __restrict__ och,
                                                unsigned short* __restrict__ sidx,
                                                unsigned short* __restrict__ sval,
                                                int* __restrict__ scnt) {
    __shared__ float smM[4][16];
    __shared__ float smS[4][16], smC[4][16];
    __shared__ float tau0s[16];
    __shared__ float taus[16];
    __shared__ float candV[16][CCAP];
    __shared__ int   ccnt[16];
    __shared__ int   ovfAny;
    __shared__ int   scnt16[16];
    __shared__ short slotI[16][16];
    __shared__ float slotV[16][16];

    int tid = threadIdx.x, w = tid >> 6, lane = tid & 63;
    int m16 = lane & 15, qd = lane >> 4;

    // XCD-aware swizzle: xcd = bid&7 owns bh slices {xcd, 8+xcd, ...}
    int bid = blockIdx.x;
    int xcd = bid & 7;
    int j   = bid >> 3;
    int bh  = ((j & 7) << 3) | xcd;   // 0..63
    int qt  = j >> 3;                 // 0..63
    int bb  = bh >> 4, h = bh & 15;
    int row0g = bb * S_ + qt * 16;
    int kbase = bb * S_;

    // Q A-frags (rows row0g+m16), k-chunks 0/1, hi+lo
    bf16x8 aH[2], aL[2];
#pragma unroll
    for (int c = 0; c < 2; c++) {
        size_t off = (size_t)(row0g + m16) * D_ + h * DH + c * 32 + qd * 8;
        aH[c] = *(const bf16x8*)(qh + off);
        aL[c] = *(const bf16x8*)(ql + off);
    }

    f32x4 Cfr[16];
#pragma unroll
    for (int t = 0; t < 16; t++) Cfr[t] = (f32x4){0.f, 0.f, 0.f, 0.f};

#pragma unroll
    for (int t = 0; t < 16; t++) {
        int n0 = w * 256 + t * 16;
        bf16x8 bH[2], bL[2];
#pragma unroll
        for (int c = 0; c < 2; c++) {
            size_t boff = (size_t)(kbase + n0 + m16) * D_ + h * DH + c * 32 + qd * 8;
            bH[c] = *(const bf16x8*)(kh + boff);
            bL[c] = *(const bf16x8*)(kl + boff);
        }
        f32x4 a = Cfr[t];
        a = __builtin_amdgcn_mfma_f32_16x16x32_bf16(aH[0], bH[0], a, 0, 0, 0);
        a = __builtin_amdgcn_mfma_f32_16x16x32_bf16(aH[1], bH[1], a, 0, 0, 0);
        a = __builtin_amdgcn_mfma_f32_16x16x32_bf16(aH[0], bL[0], a, 0, 0, 0);
        a = __builtin_amdgcn_mfma_f32_16x16x32_bf16(aH[1], bL[1], a, 0, 0, 0);
        a = __builtin_amdgcn_mfma_f32_16x16x32_bf16(aL[0], bH[0], a, 0, 0, 0);
        a = __builtin_amdgcn_mfma_f32_16x16x32_bf16(aL[1], bH[1], a, 0, 0, 0);
        Cfr[t] = a;
    }
#pragma unroll
    for (int t = 0; t < 16; t++)
#pragma unroll
        for (int r = 0; r < 4; r++) Cfr[t][r] *= 0.125f;

    // ---- row max -> tau0 ----
    float mxr[4];
#pragma unroll
    for (int r = 0; r < 4; r++) mxr[r] = -3.0e38f;
#pragma unroll
    for (int t = 0; t < 16; t++)
#pragma unroll
        for (int r = 0; r < 4; r++) mxr[r] = fmaxf(mxr[r], Cfr[t][r]);
#pragma unroll
    for (int off = 8; off >= 1; off >>= 1)
#pragma unroll
        for (int r = 0; r < 4; r++) mxr[r] = fmaxf(mxr[r], __shfl_xor(mxr[r], off, 16));
    if (m16 == 0)
#pragma unroll
        for (int r = 0; r < 4; r++) smM[w][qd * 4 + r] = mxr[r];
    if (tid < 16) ccnt[tid] = 0;
    if (tid == 0) ovfAny = 0;
    __syncthreads();
    if (tid < 16)
        tau0s[tid] = fmaxf(fmaxf(smM[0][tid], smM[1][tid]), fmaxf(smM[2][tid], smM[3][tid])) - 1.0f;
    __syncthreads();

    // ---- candidate compaction (values only; used solely to find tau) ----
#pragma unroll
    for (int t = 0; t < 16; t++)
#pragma unroll
        for (int r = 0; r < 4; r++) {
            float z = Cfr[t][r];
            int row = qd * 4 + r;
            if (z > tau0s[row]) {
                int pos = atomicAdd(&ccnt[row], 1);
                if (pos < CCAP) candV[row][pos] = z;
            }
        }
    __syncthreads();
    if (tid < 16 && ccnt[tid] > CCAP) ovfAny = 1;

    // ---- fast-path Newton over candidates: 16 threads per row ----
    int prow = tid >> 4, pc = tid & 15;
    {
        int nc = ccnt[prow];
        float tau = tau0s[prow];
        if (nc <= CCAP) {
            float z0 = (pc < nc)      ? candV[prow][pc]      : -3.0e38f;
            float z1 = (pc + 16 < nc) ? candV[prow][pc + 16] : -3.0e38f;
            float z2 = (pc + 32 < nc) ? candV[prow][pc + 32] : -3.0e38f;
            for (int it = 0; it < CCAP; it++) {
                float s = 0.f, c = 0.f;
                if (z0 > tau) { s += z0; c += 1.f; }
                if (z1 > tau) { s += z1; c += 1.f; }
                if (z2 > tau) { s += z2; c += 1.f; }
#pragma unroll
                for (int off = 8; off >= 1; off >>= 1) {
                    s += __shfl_xor(s, off, 16);
                    c += __shfl_xor(c, off, 16);
                }
                float tnew = (s - 1.f) / c;
                if (tnew > tau) tau = tnew; else break;
            }
        }
        if (pc == 0) taus[prow] = tau;   // overflow rows keep tau0
    }
    __syncthreads();

    // ---- rare fallback: full-register block Newton (rows at fixed point don't move) ----
    if (ovfAny) {
        for (int it = 0; it < 64; it++) {
            float s[4], c[4];
#pragma unroll
            for (int r = 0; r < 4; r++) { s[r] = 0.f; c[r] = 0.f; }
#pragma unroll
            for (int t = 0; t < 16; t++)
#pragma unroll
                for (int r = 0; r < 4; r++) {
                    float z = Cfr[t][r];
                    if (z > taus[qd * 4 + r]) { s[r] += z; c[r] += 1.f; }
                }
#pragma unroll
            for (int off = 8; off >= 1; off >>= 1)
#pragma unroll
                for (int r = 0; r < 4; r++) {
                    s[r] += __shfl_xor(s[r], off, 16);
                    c[r] += __shfl_xor(c[r], off, 16);
                }
            if (m16 == 0)
#pragma unroll
                for (int r = 0; r < 4; r++) {
                    smS[w][qd * 4 + r] = s[r];
                    smC[w][qd * 4 + r] = c[r];
                }
            __syncthreads();
            int done = 1;
            if (tid < 16) {
                float S = smS[0][tid] + smS[1][tid] + smS[2][tid] + smS[3][tid];
                float C = smC[0][tid] + smC[1][tid] + smC[2][tid] + smC[3][tid];
                float tnew = (S - 1.f) / C;
                if (C > 0.f && tnew > taus[tid]) { taus[tid] = tnew; done = 0; }
            }
            if (__syncthreads_and(done)) break;
        }
    }

    // ---- slot extraction from REGISTERS (correct for all rows) ----
    if (tid < 16) scnt16[tid] = 0;
    __syncthreads();
#pragma unroll
    for (int t = 0; t < 16; t++)
#pragma unroll
        for (int r = 0; r < 4; r++) {
            int row = qd * 4 + r;
            float p = Cfr[t][r] - taus[row];
            if (p > 0.f) {
                int sl = atomicAdd(&scnt16[row], 1);
                if (sl < 16) {
                    slotI[row][sl] = (short)(w * 256 + t * 16 + m16);
                    slotV[row][sl] = p;
                }
            }
        }
    __syncthreads();

    // ---- PV: lane (prow, pc) accumulates dims pc*4..pc*4+3 ----
    int nsl = min(scnt16[prow], 16);
    float4 accq = make_float4(0.f, 0.f, 0.f, 0.f);
    for (int sl = 0; sl < nsl; sl++) {
        int key = slotI[prow][sl];
        float p = slotV[prow][sl];
        float4 vv = *(const float4*)(vsh + (size_t)(kbase + key) * DH + pc * 4);
        accq.x += p * vv.x;
        accq.y += p * vv.y;
        accq.z += p * vv.z;
        accq.w += p * vv.w;
    }
    {
        unsigned short b0 = f2bf(accq.x), b1 = f2bf(accq.y), b2 = f2bf(accq.z), b3 = f2bf(accq.w);
        *(uint2*)(och + (size_t)(row0g + prow) * D_ + h * DH + pc * 4) =
            make_uint2((unsigned)b0 | ((unsigned)b1 << 16), (unsigned)b2 | ((unsigned)b3 << 16));
    }

    // ---- export slot lists for avg_reduce ----
    {
        size_t base = ((size_t)(row0g + prow) * H_ + h) * 16;
        if (pc == 0) scnt[(row0g + prow) * H_ + h] = nsl;
        if (pc < nsl) {
            sidx[base + pc] = (unsigned short)slotI[prow][pc];
            sval[base + pc] = f2bf(slotV[prow][pc]);
        }
    }
}

// ---------------- avg_attention: per-row reduction over 16 heads ----------------
__global__ __launch_bounds__(256) void avg_reduce(const unsigned short* __restrict__ sidx,
                                                  const unsigned short* __restrict__ sval,
                                                  const int* __restrict__ scnt,
                                                  float* __restrict__ avg) {
    __shared__ float accv[1024];
    int tid = threadIdx.x;
    int grow = blockIdx.x;
    for (int i = tid; i < 1024; i += 256) accv[i] = 0.f;
    __syncthreads();
    int h = tid >> 4, sl = tid & 15;
    int n = scnt[grow * H_ + h];
    if (sl < n) {
        size_t base = ((size_t)grow * H_ + h) * 16;
        int idx = sidx[base + sl];
        float v = bf2f(sval[base + sl]);
        atomicAdd(&accv[idx], v);
    }
    __syncthreads();
    float* dst = avg + (size_t)grow * S_;
    for (int i = tid; i < 256; i += 256) {
        float4 o;
        o.x = accv[i * 4 + 0] * 0.0625f;
        o.y = accv[i * 4 + 1] * 0.0625f;
        o.z = accv[i * 4 + 2] * 0.0625f;
        o.w = accv[i * 4 + 3] * 0.0625f;
        *(float4*)(dst + i * 4) = o;
    }
}

extern "C" void kernel_launch(void* const* d_in, const int* in_sizes, int n_in,
                              void* d_out, int out_size, void* d_ws, size_t ws_size,
                              hipStream_t stream) {
    const float* x  = (const float*)d_in[0];
    const float* Wq = (const float*)d_in[1];
    const float* bq = (const float*)d_in[2];
    const float* Wk = (const float*)d_in[3];
    const float* bk = (const float*)d_in[4];
    const float* Wv = (const float*)d_in[5];
    const float* bv = (const float*)d_in[6];
    const float* Wo = (const float*)d_in[7];
    const float* bo = (const float*)d_in[8];

    float* xout = (float*)d_out;                   // (B,S,D)
    float* avg  = xout + (size_t)BS * D_;          // (B,S,S)

    char* ws = (char*)d_ws;
    unsigned short* qhB  = (unsigned short*)(ws + 0);               // 8 MB
    unsigned short* qlB  = (unsigned short*)(ws + (8u << 20));      // 8 MB
    unsigned short* khB  = (unsigned short*)(ws + (16u << 20));     // 8 MB
    unsigned short* klB  = (unsigned short*)(ws + (24u << 20));     // 8 MB
    unsigned short* WTh  = (unsigned short*)(ws + (32u << 20));     // 2 MB (alias: sidx)
    unsigned short* WTl  = (unsigned short*)(ws + (34u << 20));     // 2 MB (alias: sval)
    unsigned short* WoTh = (unsigned short*)(ws + (36u << 20));     // 2 MB
    unsigned short* ochB = (unsigned short*)(ws + (38u << 20));     // 8 MB
    float* vshb = (float*)(ws + (46u << 20));                       // 1 MB
    float* Wvsh = (float*)(ws + (47u << 20));                       // 256 KB (alias: scnt)
    float* bvsh = (float*)(ws + (47u << 20) + (320u << 10));        // tiny
    unsigned short* sidx = WTh;
    unsigned short* sval = WTl;
    int* scnt = (int*)Wvsh;

    dim3 ggrid(D_ / 64, BS / 128);

    wTsplit<<<1024, 256, 0, stream>>>(Wo, WoTh, nullptr, 0);
    wv_reduce_kernel<<<256, 256, 0, stream>>>(Wv, bv, Wvsh, bvsh);
    sgemm64<<<dim3(1, BS / 64), 256, 0, stream>>>(x, Wvsh, bvsh, vshb, BS, DH, D_);

    wTsplit<<<1024, 256, 0, stream>>>(Wq, WTh, WTl, 1);
    bgemm<1, 1><<<ggrid, 256, 0, stream>>>(x, nullptr, WTh, WTl, bq, nullptr, qhB, qlB);
    wTsplit<<<1024, 256, 0, stream>>>(Wk, WTh, WTl, 1);
    bgemm<1, 1><<<ggrid, 256, 0, stream>>>(x, nullptr, WTh, WTl, bk, nullptr, khB, klB);

    attn7<<<4096, 256, 0, stream>>>(qhB, qlB, khB, klB, vshb, ochB, sidx, sval, scnt);
    avg_reduce<<<4096, 256, 0, stream>>>(sidx, sval, scnt, avg);

    bgemm<0, 0><<<ggrid, 256, 0, stream>>>(nullptr, ochB, WoTh, nullptr, bo, xout, nullptr, nullptr);
}

// Round 7
// 424.818 us; speedup vs baseline: 4.5362x; 1.0560x over previous
//
#include <hip/hip_runtime.h>

#define B_  4
#define S_  1024
#define D_  1024
#define H_  16
#define DH  64
#define BS  4096   // B_*S_

typedef __bf16 bf16x8 __attribute__((ext_vector_type(8)));
typedef float  f32x4  __attribute__((ext_vector_type(4)));

__device__ __forceinline__ unsigned short f2bf(float f) {
    __bf16 b = (__bf16)f;
    return __builtin_bit_cast(unsigned short, b);
}
__device__ __forceinline__ float bf2f(unsigned short u) {
    return (float)__builtin_bit_cast(__bf16, u);
}

// ---------------- fused prep: wTsplit(Wq), wTsplit(Wk), wTsplit(Wo, hi-only), wv_reduce ----------------
__global__ __launch_bounds__(256) void prep(const float* __restrict__ Wq,
                                            const float* __restrict__ Wk,
                                            const float* __restrict__ Wo,
                                            const float* __restrict__ Wv,
                                            const float* __restrict__ bv,
                                            unsigned short* __restrict__ WqTh,
                                            unsigned short* __restrict__ WqTl,
                                            unsigned short* __restrict__ WkTh,
                                            unsigned short* __restrict__ WkTl,
                                            unsigned short* __restrict__ WoTh,
                                            float* __restrict__ Wvsh,
                                            float* __restrict__ bvsh) {
    __shared__ float tile[32][33];
    int bid = blockIdx.x, tid = threadIdx.x;
    if (bid < 3072) {
        const float* W;
        unsigned short *Th, *Tl;
        int wantLo;
        if (bid < 1024)      { W = Wq; Th = WqTh; Tl = WqTl; wantLo = 1; }
        else if (bid < 2048) { W = Wk; Th = WkTh; Tl = WkTl; wantLo = 1; bid -= 1024; }
        else                 { W = Wo; Th = WoTh; Tl = nullptr; wantLo = 0; bid -= 2048; }
        int tn = bid & 31, tk = bid >> 5;
        int r = tid >> 3, c4 = (tid & 7) * 4;
        float4 v = *(const float4*)(W + (size_t)(tk * 32 + r) * D_ + tn * 32 + c4);
        tile[r][c4 + 0] = v.x;
        tile[r][c4 + 1] = v.y;
        tile[r][c4 + 2] = v.z;
        tile[r][c4 + 3] = v.w;
        __syncthreads();
        unsigned short hh[4], ll[4];
#pragma unroll
        for (int i = 0; i < 4; i++) {
            float f = tile[c4 + i][r];
            hh[i] = f2bf(f);
            ll[i] = f2bf(f - bf2f(hh[i]));
        }
        size_t off = (size_t)(tn * 32 + r) * D_ + tk * 32 + c4;
        *(uint2*)(Th + off) = make_uint2((unsigned)hh[0] | ((unsigned)hh[1] << 16),
                                         (unsigned)hh[2] | ((unsigned)hh[3] << 16));
        if (wantLo)
            *(uint2*)(Tl + off) = make_uint2((unsigned)ll[0] | ((unsigned)ll[1] << 16),
                                             (unsigned)ll[2] | ((unsigned)ll[3] << 16));
    } else {
        int e = (bid - 3072) * 256 + tid;
        if (e < D_ * DH) {
            int d = e >> 6, j = e & 63;
            float s = 0.f;
#pragma unroll
            for (int hh = 0; hh < H_; hh++) s += Wv[d * D_ + hh * DH + j];
            Wvsh[e] = s * (1.f / 16.f);
        }
        if (e < DH) {
            float s = 0.f;
#pragma unroll
            for (int hh = 0; hh < H_; hh++) s += bv[hh * DH + e];
            bvsh[e] = s * (1.f / 16.f);
        }
    }
}

// ---------------- 64x64 fp32 SGEMM + bias (v_shared, N=64) ----------------
__global__ __launch_bounds__(256) void sgemm64(const float* __restrict__ A,
                                               const float* __restrict__ Bm,
                                               const float* __restrict__ bias,
                                               float* __restrict__ C,
                                               int M, int N, int K) {
    __shared__ float As[16][68];
    __shared__ float Bs[16][68];
    int tid = threadIdx.x;
    int bm = blockIdx.y, bn = blockIdx.x;
    int tx = tid & 15, ty = tid >> 4;
    int la_m = tid >> 2, la_k4 = (tid & 3) * 4;
    int lb_k = tid >> 4, lb_n4 = (tid & 15) * 4;

    float acc[4][4];
#pragma unroll
    for (int i = 0; i < 4; i++)
#pragma unroll
        for (int j = 0; j < 4; j++) acc[i][j] = 0.f;

    for (int k0 = 0; k0 < K; k0 += 16) {
        float4 a4 = *(const float4*)(A + (size_t)(bm * 64 + la_m) * K + k0 + la_k4);
        float4 b4 = *(const float4*)(Bm + (size_t)(k0 + lb_k) * N + bn * 64 + lb_n4);
        __syncthreads();
        As[la_k4 + 0][la_m] = a4.x;
        As[la_k4 + 1][la_m] = a4.y;
        As[la_k4 + 2][la_m] = a4.z;
        As[la_k4 + 3][la_m] = a4.w;
        *(float4*)&Bs[lb_k][lb_n4] = b4;
        __syncthreads();
#pragma unroll
        for (int kk = 0; kk < 16; kk++) {
            float4 a0 = *(float4*)&As[kk][ty * 4];
            float4 b0 = *(float4*)&Bs[kk][tx * 4];
            float av[4] = {a0.x, a0.y, a0.z, a0.w};
            float bw[4] = {b0.x, b0.y, b0.z, b0.w};
#pragma unroll
            for (int i = 0; i < 4; i++)
#pragma unroll
                for (int j = 0; j < 4; j++) acc[i][j] += av[i] * bw[j];
        }
    }
#pragma unroll
    for (int r = 0; r < 4; r++) {
        int row = bm * 64 + ty * 4 + r;
        int col = bn * 64 + tx * 4;
        float4 bb = *(const float4*)(bias + col);
        float4 o;
        o.x = acc[r][0] + bb.x;
        o.y = acc[r][1] + bb.y;
        o.z = acc[r][2] + bb.z;
        o.w = acc[r][3] + bb.w;
        *(float4*)(C + (size_t)row * N + col) = o;
    }
}

// ---------------- bf16 MFMA GEMM, 128x64 tile, B^T layout ----------------
// oscale: output scale applied AFTER bias (exact for powers of 2).
template<int HILO, int OUTMODE>
__global__ __launch_bounds__(256) void bgemm(const float* __restrict__ Afp,
                                             const unsigned short* __restrict__ Abf,
                                             const unsigned short* __restrict__ Bh,
                                             const unsigned short* __restrict__ Bl,
                                             const float* __restrict__ bias,
                                             float oscale,
                                             float* __restrict__ Cf,
                                             unsigned short* __restrict__ Ch,
                                             unsigned short* __restrict__ Cl) {
    __shared__ unsigned short AhS[128 * 32];
    __shared__ unsigned short AlS[HILO ? 128 * 32 : 8];
    __shared__ unsigned short BhS[64 * 32];
    __shared__ unsigned short BlS[HILO ? 64 * 32 : 8];

    int tid = threadIdx.x;
    int bn = blockIdx.x, bm = blockIdx.y;
    int w = tid >> 6, lane = tid & 63;
    int m16 = lane & 15, qd = lane >> 4;
    int rh = (w >> 1) * 64, ch = (w & 1) * 32;

    f32x4 acc[4][2];
#pragma unroll
    for (int it = 0; it < 4; it++)
#pragma unroll
        for (int jt = 0; jt < 2; jt++) acc[it][jt] = (f32x4){0.f, 0.f, 0.f, 0.f};

    for (int k0 = 0; k0 < D_; k0 += 32) {
        __syncthreads();
        if (HILO) {
#pragma unroll
            for (int i = 0; i < 2; i++) {
                int idx = i * 256 + tid;
                int row = idx >> 2, seg = idx & 3;
                const float* src = Afp + (size_t)(bm * 128 + row) * D_ + k0 + seg * 8;
                float4 v0 = *(const float4*)src;
                float4 v1 = *(const float4*)(src + 4);
                float vv[8] = {v0.x, v0.y, v0.z, v0.w, v1.x, v1.y, v1.z, v1.w};
                unsigned int hw[4], lw[4];
#pragma unroll
                for (int j = 0; j < 4; j++) {
                    unsigned short h0 = f2bf(vv[2 * j]), h1 = f2bf(vv[2 * j + 1]);
                    unsigned short l0 = f2bf(vv[2 * j] - bf2f(h0));
                    unsigned short l1 = f2bf(vv[2 * j + 1] - bf2f(h1));
                    hw[j] = (unsigned)h0 | ((unsigned)h1 << 16);
                    lw[j] = (unsigned)l0 | ((unsigned)l1 << 16);
                }
                *(uint4*)((char*)AhS + idx * 16) = make_uint4(hw[0], hw[1], hw[2], hw[3]);
                *(uint4*)((char*)AlS + idx * 16) = make_uint4(lw[0], lw[1], lw[2], lw[3]);
            }
        } else {
#pragma unroll
            for (int i = 0; i < 2; i++) {
                int idx = i * 256 + tid;
                int row = idx >> 2, seg = idx & 3;
                uint4 v = *(const uint4*)(Abf + (size_t)(bm * 128 + row) * D_ + k0 + seg * 8);
                *(uint4*)((char*)AhS + idx * 16) = v;
            }
        }
        {
            int row = tid >> 2, seg = tid & 3;
            uint4 v = *(const uint4*)(Bh + (size_t)(bn * 64 + row) * D_ + k0 + seg * 8);
            *(uint4*)((char*)BhS + tid * 16) = v;
            if (HILO) {
                uint4 v2 = *(const uint4*)(Bl + (size_t)(bn * 64 + row) * D_ + k0 + seg * 8);
                *(uint4*)((char*)BlS + tid * 16) = v2;
            }
        }
        __syncthreads();
        bf16x8 ah[4], al[4], bh2[2], bl2[2];
#pragma unroll
        for (int it = 0; it < 4; it++) {
            ah[it] = *(const bf16x8*)((char*)AhS + (rh + it * 16 + m16) * 64 + qd * 16);
            if (HILO) al[it] = *(const bf16x8*)((char*)AlS + (rh + it * 16 + m16) * 64 + qd * 16);
        }
#pragma unroll
        for (int jt = 0; jt < 2; jt++) {
            bh2[jt] = *(const bf16x8*)((char*)BhS + (ch + jt * 16 + m16) * 64 + qd * 16);
            if (HILO) bl2[jt] = *(const bf16x8*)((char*)BlS + (ch + jt * 16 + m16) * 64 + qd * 16);
        }
#pragma unroll
        for (int it = 0; it < 4; it++)
#pragma unroll
            for (int jt = 0; jt < 2; jt++) {
                acc[it][jt] = __builtin_amdgcn_mfma_f32_16x16x32_bf16(ah[it], bh2[jt], acc[it][jt], 0, 0, 0);
                if (HILO) {
                    acc[it][jt] = __builtin_amdgcn_mfma_f32_16x16x32_bf16(ah[it], bl2[jt], acc[it][jt], 0, 0, 0);
                    acc[it][jt] = __builtin_amdgcn_mfma_f32_16x16x32_bf16(al[it], bh2[jt], acc[it][jt], 0, 0, 0);
                }
            }
    }
#pragma unroll
    for (int it = 0; it < 4; it++)
#pragma unroll
        for (int jt = 0; jt < 2; jt++)
#pragma unroll
            for (int r = 0; r < 4; r++) {
                int R = bm * 128 + rh + it * 16 + qd * 4 + r;
                int Cc = bn * 64 + ch + jt * 16 + m16;
                float v = (acc[it][jt][r] + bias[Cc]) * oscale;
                if (OUTMODE == 0) {
                    Cf[(size_t)R * D_ + Cc] = v;
                } else {
                    unsigned short h0 = f2bf(v);
                    Ch[(size_t)R * D_ + Cc] = h0;
                    Cl[(size_t)R * D_ + Cc] = f2bf(v - bf2f(h0));
                }
            }
}

// ---------------- fused attention v8 ----------------
// vs v7: (1) loads batched 4-deep for memory pipelining, (2) Q pre-scaled by 1/8
// (no per-element scale), (3) compaction stores (val,idx) so fast-path slot
// extraction is a 3-element list scan; register fallback kept for overflow.
#define CCAP 48
__global__ __launch_bounds__(256, 2) void attn8(const unsigned short* __restrict__ qh,
                                                const unsigned short* __restrict__ ql,
                                                const unsigned short* __restrict__ kh,
                                                const unsigned short* __restrict__ kl,
                                                const float* __restrict__ vsh,
                                                unsigned short* __restrict__ och,
                                                unsigned short* __restrict__ sidx,
                                                unsigned short* __restrict__ sval,
                                                int* __restrict__ scnt) {
    __shared__ float smM[4][16];
    __shared__ float smS[4][16], smC[4][16];
    __shared__ float tau0s[16];
    __shared__ float taus[16];
    __shared__ float candV[16][CCAP];
    __shared__ short candI[16][CCAP];
    __shared__ int   ccnt[16];
    __shared__ int   ovfAny;
    __shared__ int   scnt16[16];
    __shared__ short slotI[16][16];
    __shared__ float slotV[16][16];

    int tid = threadIdx.x, w = tid >> 6, lane = tid & 63;
    int m16 = lane & 15, qd = lane >> 4;

    // XCD-aware swizzle: xcd = bid&7 owns bh slices {xcd, 8+xcd, ...}
    int bid = blockIdx.x;
    int xcd = bid & 7;
    int j   = bid >> 3;
    int bh  = ((j & 7) << 3) | xcd;   // 0..63
    int qt  = j >> 3;                 // 0..63
    int bb  = bh >> 4, h = bh & 15;
    int row0g = bb * S_ + qt * 16;
    int kbase = bb * S_;

    // Q A-frags (rows row0g+m16), k-chunks 0/1, hi+lo (pre-scaled by 1/8)
    bf16x8 aH[2], aL[2];
#pragma unroll
    for (int c = 0; c < 2; c++) {
        size_t off = (size_t)(row0g + m16) * D_ + h * DH + c * 32 + qd * 8;
        aH[c] = *(const bf16x8*)(qh + off);
        aL[c] = *(const bf16x8*)(ql + off);
    }

    f32x4 Cfr[16];
#pragma unroll
    for (int t = 0; t < 16; t++) Cfr[t] = (f32x4){0.f, 0.f, 0.f, 0.f};

    // ---- logits: 4 batches of 4 iters; 16 loads in flight then 24 MFMAs ----
#pragma unroll
    for (int tb = 0; tb < 4; tb++) {
        bf16x8 bH[4][2], bL[4][2];
#pragma unroll
        for (int tt = 0; tt < 4; tt++) {
            int n0 = w * 256 + (tb * 4 + tt) * 16;
#pragma unroll
            for (int c = 0; c < 2; c++) {
                size_t boff = (size_t)(kbase + n0 + m16) * D_ + h * DH + c * 32 + qd * 8;
                bH[tt][c] = *(const bf16x8*)(kh + boff);
                bL[tt][c] = *(const bf16x8*)(kl + boff);
            }
        }
#pragma unroll
        for (int tt = 0; tt < 4; tt++) {
            int t = tb * 4 + tt;
            f32x4 a = Cfr[t];
            a = __builtin_amdgcn_mfma_f32_16x16x32_bf16(aH[0], bH[tt][0], a, 0, 0, 0);
            a = __builtin_amdgcn_mfma_f32_16x16x32_bf16(aH[1], bH[tt][1], a, 0, 0, 0);
            a = __builtin_amdgcn_mfma_f32_16x16x32_bf16(aH[0], bL[tt][0], a, 0, 0, 0);
            a = __builtin_amdgcn_mfma_f32_16x16x32_bf16(aH[1], bL[tt][1], a, 0, 0, 0);
            a = __builtin_amdgcn_mfma_f32_16x16x32_bf16(aL[0], bH[tt][0], a, 0, 0, 0);
            a = __builtin_amdgcn_mfma_f32_16x16x32_bf16(aL[1], bH[tt][1], a, 0, 0, 0);
            Cfr[t] = a;
        }
    }

    // ---- row max -> tau0 ----
    float mxr[4];
#pragma unroll
    for (int r = 0; r < 4; r++) mxr[r] = -3.0e38f;
#pragma unroll
    for (int t = 0; t < 16; t++)
#pragma unroll
        for (int r = 0; r < 4; r++) mxr[r] = fmaxf(mxr[r], Cfr[t][r]);
#pragma unroll
    for (int off = 8; off >= 1; off >>= 1)
#pragma unroll
        for (int r = 0; r < 4; r++) mxr[r] = fmaxf(mxr[r], __shfl_xor(mxr[r], off, 16));
    if (m16 == 0)
#pragma unroll
        for (int r = 0; r < 4; r++) smM[w][qd * 4 + r] = mxr[r];
    if (tid < 16) ccnt[tid] = 0;
    if (tid == 0) ovfAny = 0;
    __syncthreads();
    if (tid < 16)
        tau0s[tid] = fmaxf(fmaxf(smM[0][tid], smM[1][tid]), fmaxf(smM[2][tid], smM[3][tid])) - 1.0f;
    __syncthreads();

    // ---- candidate compaction (val + idx) ----
#pragma unroll
    for (int t = 0; t < 16; t++)
#pragma unroll
        for (int r = 0; r < 4; r++) {
            float z = Cfr[t][r];
            int row = qd * 4 + r;
            if (z > tau0s[row]) {
                int pos = atomicAdd(&ccnt[row], 1);
                if (pos < CCAP) {
                    candV[row][pos] = z;
                    candI[row][pos] = (short)(w * 256 + t * 16 + m16);
                }
            }
        }
    __syncthreads();
    if (tid < 16 && ccnt[tid] > CCAP) ovfAny = 1;

    // ---- fast-path Newton over candidates: 16 threads per row ----
    int prow = tid >> 4, pc = tid & 15;
    int nc = ccnt[prow];
    float tau = tau0s[prow];
    float z0 = -3.0e38f, z1 = -3.0e38f, z2 = -3.0e38f;
    if (nc <= CCAP) {
        z0 = (pc < nc)      ? candV[prow][pc]      : -3.0e38f;
        z1 = (pc + 16 < nc) ? candV[prow][pc + 16] : -3.0e38f;
        z2 = (pc + 32 < nc) ? candV[prow][pc + 32] : -3.0e38f;
        for (int it = 0; it < CCAP; it++) {
            float s = 0.f, c = 0.f;
            if (z0 > tau) { s += z0; c += 1.f; }
            if (z1 > tau) { s += z1; c += 1.f; }
            if (z2 > tau) { s += z2; c += 1.f; }
#pragma unroll
            for (int off = 8; off >= 1; off >>= 1) {
                s += __shfl_xor(s, off, 16);
                c += __shfl_xor(c, off, 16);
            }
            float tnew = (s - 1.f) / c;
            if (tnew > tau) tau = tnew; else break;
        }
    }
    if (pc == 0) taus[prow] = tau;   // overflow rows keep tau0
    if (tid < 16) scnt16[tid] = 0;
    __syncthreads();

    if (!ovfAny) {
        // ---- fast-path slot extraction from candidate list (3 entries/lane) ----
        if (z0 > tau) {
            int sl = atomicAdd(&scnt16[prow], 1);
            if (sl < 16) { slotI[prow][sl] = candI[prow][pc]; slotV[prow][sl] = z0 - tau; }
        }
        if (z1 > tau) {
            int sl = atomicAdd(&scnt16[prow], 1);
            if (sl < 16) { slotI[prow][sl] = candI[prow][pc + 16]; slotV[prow][sl] = z1 - tau; }
        }
        if (z2 > tau) {
            int sl = atomicAdd(&scnt16[prow], 1);
            if (sl < 16) { slotI[prow][sl] = candI[prow][pc + 32]; slotV[prow][sl] = z2 - tau; }
        }
        __syncthreads();
    } else {
        // ---- rare fallback: full-register block Newton + register extraction ----
        for (int it = 0; it < 64; it++) {
            float s[4], c[4];
#pragma unroll
            for (int r = 0; r < 4; r++) { s[r] = 0.f; c[r] = 0.f; }
#pragma unroll
            for (int t = 0; t < 16; t++)
#pragma unroll
                for (int r = 0; r < 4; r++) {
                    float z = Cfr[t][r];
                    if (z > taus[qd * 4 + r]) { s[r] += z; c[r] += 1.f; }
                }
#pragma unroll
            for (int off = 8; off >= 1; off >>= 1)
#pragma unroll
                for (int r = 0; r < 4; r++) {
                    s[r] += __shfl_xor(s[r], off, 16);
                    c[r] += __shfl_xor(c[r], off, 16);
                }
            if (m16 == 0)
#pragma unroll
                for (int r = 0; r < 4; r++) {
                    smS[w][qd * 4 + r] = s[r];
                    smC[w][qd * 4 + r] = c[r];
                }
            __syncthreads();
            int done = 1;
            if (tid < 16) {
                float S = smS[0][tid] + smS[1][tid] + smS[2][tid] + smS[3][tid];
                float C = smC[0][tid] + smC[1][tid] + smC[2][tid] + smC[3][tid];
                float tnew = (S - 1.f) / C;
                if (C > 0.f && tnew > taus[tid]) { taus[tid] = tnew; done = 0; }
            }
            if (__syncthreads_and(done)) break;
        }
#pragma unroll
        for (int t = 0; t < 16; t++)
#pragma unroll
            for (int r = 0; r < 4; r++) {
                int row = qd * 4 + r;
                float p = Cfr[t][r] - taus[row];
                if (p > 0.f) {
                    int sl = atomicAdd(&scnt16[row], 1);
                    if (sl < 16) {
                        slotI[row][sl] = (short)(w * 256 + t * 16 + m16);
                        slotV[row][sl] = p;
                    }
                }
            }
        __syncthreads();
    }

    // ---- PV: lane (prow, pc) accumulates dims pc*4..pc*4+3 ----
    int nsl = min(scnt16[prow], 16);
    float4 accq = make_float4(0.f, 0.f, 0.f, 0.f);
    for (int sl = 0; sl < nsl; sl++) {
        int key = slotI[prow][sl];
        float p = slotV[prow][sl];
        float4 vv = *(const float4*)(vsh + (size_t)(kbase + key) * DH + pc * 4);
        accq.x += p * vv.x;
        accq.y += p * vv.y;
        accq.z += p * vv.z;
        accq.w += p * vv.w;
    }
    {
        unsigned short b0 = f2bf(accq.x), b1 = f2bf(accq.y), b2 = f2bf(accq.z), b3 = f2bf(accq.w);
        *(uint2*)(och + (size_t)(row0g + prow) * D_ + h * DH + pc * 4) =
            make_uint2((unsigned)b0 | ((unsigned)b1 << 16), (unsigned)b2 | ((unsigned)b3 << 16));
    }

    // ---- export slot lists for avg_reduce ----
    {
        size_t base = ((size_t)(row0g + prow) * H_ + h) * 16;
        if (pc == 0) scnt[(row0g + prow) * H_ + h] = nsl;
        if (pc < nsl) {
            sidx[base + pc] = (unsigned short)slotI[prow][pc];
            sval[base + pc] = f2bf(slotV[prow][pc]);
        }
    }
}

// ---------------- avg_attention: per-row reduction over 16 heads ----------------
__global__ __launch_bounds__(256) void avg_reduce(const unsigned short* __restrict__ sidx,
                                                  const unsigned short* __restrict__ sval,
                                                  const int* __restrict__ scnt,
                                                  float* __restrict__ avg) {
    __shared__ float accv[1024];
    int tid = threadIdx.x;
    int grow = blockIdx.x;
    for (int i = tid; i < 1024; i += 256) accv[i] = 0.f;
    __syncthreads();
    int h = tid >> 4, sl = tid & 15;
    int n = scnt[grow * H_ + h];
    if (sl < n) {
        size_t base = ((size_t)grow * H_ + h) * 16;
        int idx = sidx[base + sl];
        float v = bf2f(sval[base + sl]);
        atomicAdd(&accv[idx], v);
    }
    __syncthreads();
    float* dst = avg + (size_t)grow * S_;
    for (int i = tid; i < 256; i += 256) {
        float4 o;
        o.x = accv[i * 4 + 0] * 0.0625f;
        o.y = accv[i * 4 + 1] * 0.0625f;
        o.z = accv[i * 4 + 2] * 0.0625f;
        o.w = accv[i * 4 + 3] * 0.0625f;
        *(float4*)(dst + i * 4) = o;
    }
}

extern "C" void kernel_launch(void* const* d_in, const int* in_sizes, int n_in,
                              void* d_out, int out_size, void* d_ws, size_t ws_size,
                              hipStream_t stream) {
    const float* x  = (const float*)d_in[0];
    const float* Wq = (const float*)d_in[1];
    const float* bq = (const float*)d_in[2];
    const float* Wk = (const float*)d_in[3];
    const float* bk = (const float*)d_in[4];
    const float* Wv = (const float*)d_in[5];
    const float* bv = (const float*)d_in[6];
    const float* Wo = (const float*)d_in[7];
    const float* bo = (const float*)d_in[8];

    float* xout = (float*)d_out;                   // (B,S,D)
    float* avg  = xout + (size_t)BS * D_;          // (B,S,S)

    char* ws = (char*)d_ws;
    unsigned short* qhB  = (unsigned short*)(ws + 0);               // 8 MB
    unsigned short* qlB  = (unsigned short*)(ws + (8u << 20));      // 8 MB
    unsigned short* khB  = (unsigned short*)(ws + (16u << 20));     // 8 MB
    unsigned short* klB  = (unsigned short*)(ws + (24u << 20));     // 8 MB
    unsigned short* WqTh = (unsigned short*)(ws + (32u << 20));     // 2 MB
    unsigned short* WqTl = (unsigned short*)(ws + (34u << 20));     // 2 MB
    unsigned short* WkTh = (unsigned short*)(ws + (36u << 20));     // 2 MB
    unsigned short* WkTl = (unsigned short*)(ws + (38u << 20));     // 2 MB
    unsigned short* ochB = WqTh;                                    // 8 MB alias (32..40), dead after bgemms
    unsigned short* WoTh = (unsigned short*)(ws + (40u << 20));     // 2 MB
    float* vshb = (float*)(ws + (42u << 20));                       // 1 MB
    float* Wvsh = (float*)(ws + (43u << 20));                       // 256 KB
    float* bvsh = (float*)(ws + (43u << 20) + (300u << 10));        // tiny
    unsigned short* sidx = (unsigned short*)(ws + (44u << 20));     // 2 MB
    unsigned short* sval = (unsigned short*)(ws + (46u << 20));     // 2 MB
    int* scnt = (int*)(ws + (48u << 20));                           // 256 KB

    dim3 ggrid(D_ / 64, BS / 128);

    prep<<<3328, 256, 0, stream>>>(Wq, Wk, Wo, Wv, bv, WqTh, WqTl, WkTh, WkTl, WoTh, Wvsh, bvsh);
    bgemm<1, 1><<<ggrid, 256, 0, stream>>>(x, nullptr, WqTh, WqTl, bq, 0.125f, nullptr, qhB, qlB);
    bgemm<1, 1><<<ggrid, 256, 0, stream>>>(x, nullptr, WkTh, WkTl, bk, 1.0f, nullptr, khB, klB);
    sgemm64<<<dim3(1, BS / 64), 256, 0, stream>>>(x, Wvsh, bvsh, vshb, BS, DH, D_);
    attn8<<<4096, 256, 0, stream>>>(qhB, qlB, khB, klB, vshb, ochB, sidx, sval, scnt);
    avg_reduce<<<4096, 256, 0, stream>>>(sidx, sval, scnt, avg);
    bgemm<0, 0><<<ggrid, 256, 0, stream>>>(nullptr, ochB, WoTh, nullptr, bo, 1.0f, xout, nullptr, nullptr);
}